// Round 8
// baseline (302.821 us; speedup 1.0000x reference)
//
#include <hip/hip_runtime.h>
#include <hip/hip_cooperative_groups.h>

namespace cg = cooperative_groups;

#define HW_ 1024

typedef __attribute__((ext_vector_type(8))) short bf16x8;   // 8 bf16 = 4 VGPRs
typedef __attribute__((ext_vector_type(4))) short bf16x4;   // 8 B
typedef __attribute__((ext_vector_type(4))) float f32x4;

__device__ inline unsigned short f2bf(float f) {            // RNE f32->bf16
  unsigned int u = __float_as_uint(f);
  u += 0x7FFF + ((u >> 16) & 1);
  return (unsigned short)(u >> 16);
}
__device__ inline unsigned short f2bf_fast(float f) {       // ties-away (2 ops)
  return (unsigned short)((__float_as_uint(f) + 0x8000u) >> 16);
}
__device__ inline float bf2f(unsigned short h) {
  return __uint_as_float(((unsigned int)h) << 16);
}
__device__ inline void async_copy16(const void* g, void* l) {
  __builtin_amdgcn_global_load_lds(
      (const __attribute__((address_space(1))) unsigned int*)g,
      (__attribute__((address_space(3))) unsigned int*)l, 16, 0, 0);
}

// ---------------------------------------------------------------------------
// mega: the whole pipeline in ONE cooperative kernel. grid 256 x 512 thr
// (1 block/CU), 4 grid.sync()s replace 4 launch gaps + 5 kernel tails.
// P0 marshal | P1 qgemm (X-stage shared by both M-halves) | P2 convkv |
// P3 attn (K/V stage shared by qc-pair) | P4 out-GEMM (X tile shared).
// All phase bodies = R7 kernels verbatim, re-indexed for 8 waves.
// LDS union: max 142784 B (convkv phase).
// ---------------------------------------------------------------------------
__global__ __launch_bounds__(512) void mega(
    const float* __restrict__ kv,
    const float* __restrict__ Wq, const float* __restrict__ Wk,
    const float* __restrict__ Wv, const float* __restrict__ Wo,
    const float* __restrict__ Woff1, const float* __restrict__ boff1,
    const float* __restrict__ Woff2, const float* __restrict__ boff2,
    const float* __restrict__ bout, const float* __restrict__ Xf,
    float* __restrict__ out,
    short* __restrict__ WH, short* __restrict__ WL, short* __restrict__ wb,
    float* __restrict__ kvT, short* __restrict__ qt,
    short* __restrict__ kt, short* __restrict__ vt,
    short* __restrict__ bufBh, short* __restrict__ bufBl)
{
  __shared__ __align__(16) char SM[142784];
  cg::grid_group grid = cg::this_grid();

  const int bid  = blockIdx.x;          // 256
  const int t    = threadIdx.x;         // 512
  const int w    = t >> 6;              // 0..7
  const int lane = t & 63;
  const int ln   = lane & 15;
  const int qd   = lane >> 4;

  // ======================= P0: marshal =======================
  {
    auto T = (float (*)[33])SM;         // [256][33] = 33.8 KB
    // kvT transpose: one 32p x 256c tile per block
    int b = bid >> 5, p0 = (bid & 31) * 32;
    int pp = t & 31, cg16 = t >> 5;     // cg16 0..15
#pragma unroll
    for (int i = 0; i < 16; ++i) {
      int c = cg16 * 16 + i;
      T[c][pp] = kv[((size_t)(b * 256 + c)) * HW_ + p0 + pp];
    }
    __syncthreads();
#pragma unroll
    for (int r = 0; r < 4; ++r) {
      int e = t + 512 * r;
      int c4 = (e & 63) * 4, pp2 = e >> 6;
      float4 v4;
      v4.x = T[c4 + 0][pp2];
      v4.y = T[c4 + 1][pp2];
      v4.z = T[c4 + 2][pp2];
      v4.w = T[c4 + 3][pp2];
      *(float4*)&kvT[((size_t)(b * 1024 + p0 + pp2)) * 256 + c4] = v4;
    }
    // wsplit: 262144 floats over 256 blocks x 256 threads x f32x4
    if (t < 256) {
      int lg = bid * 1024 + t * 4;
      int mat = lg >> 16;               // 0..3 = Wq,Wk,Wv,Wout
      int loc = lg & 65535;
      const float* W = (mat == 0) ? Wq : (mat == 1) ? Wk : (mat == 2) ? Wv : Wo;
      float4 f4 = *(const float4*)&W[loc];
      float f[4] = {f4.x, f4.y, f4.z, f4.w};
      bf16x4 h4, l4;
#pragma unroll
      for (int j = 0; j < 4; ++j) {
        unsigned short h = f2bf(f[j]);
        h4[j] = (short)h;
        l4[j] = (short)f2bf(f[j] - bf2f(h));
      }
      int r = loc >> 8, c = loc & 255;
      int mtile = r >> 4, k0s = c >> 5;
      int lane_ = ((c >> 3) & 3) * 16 + (r & 15);
      int pidx = (((mtile * 8 + k0s) * 64 + lane_) * 8) + (c & 7);
      *(bf16x4*)&WH[mat * 65536 + pidx] = h4;
      *(bf16x4*)&WL[mat * 65536 + pidx] = l4;
    }
    // conv weight repack: 294912 elems over 256 blocks x 288 threads x 4
    if (t < 288) {
      int e0 = bid * 1152 + t * 4;
      int c = e0 & 255;
      int o = (e0 >> 8) & 127;
      int tap = e0 >> 15;
      bf16x4 h4;
#pragma unroll
      for (int j = 0; j < 4; ++j)
        h4[j] = (short)f2bf(Woff1[((size_t)(o * 256 + c + j)) * 9 + tap]);
      int otile = o >> 4, c0s = c >> 5;
      int lane_ = ((c >> 3) & 3) * 16 + (o & 15);
      int widx = ((((tap * 8 + otile) * 8 + c0s) * 64 + lane_) * 8) + (c & 7);
      *(bf16x4*)&wb[widx] = h4;
    }
  }
  grid.sync();

  // ======================= P1: Q-GEMM =======================
  // one-shot X stage (32p x 256c hi/lo, 33 KB) shared by BOTH M-halves.
  {
    auto Bsh = (short (*)[264])(SM);
    auto Bsl = (short (*)[264])(SM + 16896);
    const int bp0 = bid * 32;
    const int bB = bp0 >> 10, p0l = bp0 & 1023;
    {
      int pp = t & 31, cs = t >> 5;     // cs 0..15 -> 16 c's each
      float fv[16];
#pragma unroll
      for (int j = 0; j < 16; ++j)
        fv[j] = Xf[((size_t)(bB * 256 + cs * 16 + j)) * HW_ + p0l + pp];
#pragma unroll
      for (int g = 0; g < 4; ++g) {
        bf16x4 h4, l4;
#pragma unroll
        for (int j = 0; j < 4; ++j) {
          float f = fv[g * 4 + j];
          unsigned short h = f2bf(f);
          h4[j] = (short)h;
          l4[j] = (short)f2bf(f - bf2f(h));
        }
        *(bf16x4*)&Bsh[pp][cs * 16 + g * 4] = h4;
        *(bf16x4*)&Bsl[pp][cs * 16 + g * 4] = l4;
      }
    }
    __syncthreads();

    const int mh = w >> 2, ww = w & 3;
    const int mb = mh * 8 + ww * 2;
    f32x4 acc[2][2] = {};
#pragma unroll
    for (int k0 = 0; k0 < 256; k0 += 32) {
      const int k0s = k0 >> 5;
      bf16x8 Ah[2], Al[2], Bh[2], Bl[2];
#pragma unroll
      for (int mt = 0; mt < 2; ++mt) {
        size_t wi = ((size_t)(((mb + mt) * 8 + k0s) * 64 + lane)) * 8;
        Ah[mt] = *(const bf16x8*)&WH[wi];
        Al[mt] = *(const bf16x8*)&WL[wi];
      }
#pragma unroll
      for (int nt = 0; nt < 2; ++nt) {
        Bh[nt] = *(const bf16x8*)&Bsh[nt * 16 + ln][k0 + qd * 8];
        Bl[nt] = *(const bf16x8*)&Bsl[nt * 16 + ln][k0 + qd * 8];
      }
#pragma unroll
      for (int mt = 0; mt < 2; ++mt)
#pragma unroll
        for (int nt = 0; nt < 2; ++nt) {
          acc[mt][nt] = __builtin_amdgcn_mfma_f32_16x16x32_bf16(Ah[mt], Bh[nt], acc[mt][nt], 0, 0, 0);
          acc[mt][nt] = __builtin_amdgcn_mfma_f32_16x16x32_bf16(Ah[mt], Bl[nt], acc[mt][nt], 0, 0, 0);
          acc[mt][nt] = __builtin_amdgcn_mfma_f32_16x16x32_bf16(Al[mt], Bh[nt], acc[mt][nt], 0, 0, 0);
        }
    }

    const int om = mh * 128 + ww * 32;
    const float sc = 0.25506063286f;    // (1/sqrt32)*log2(e)
#pragma unroll
    for (int mt = 0; mt < 2; ++mt)
#pragma unroll
      for (int nt = 0; nt < 2; ++nt) {
        int bp = bp0 + nt * 16 + ln;
        int b = bp >> 10, p = bp & 1023;
#pragma unroll
        for (int i = 0; i < 4; ++i) {
          int o = om + mt * 16 + qd * 4 + i;
          int h = o >> 5, d = o & 31;
          qt[(((size_t)(b * 8 + h)) * 1024 + p) * 32 + d] = (short)f2bf(acc[mt][nt][i] * sc);
        }
        int ob = om + mt * 16 + qd * 4;
        bf16x4 h4, l4;
#pragma unroll
        for (int i = 0; i < 4; ++i) {
          float f = acc[mt][nt][i];
          unsigned short h = f2bf(f);
          h4[i] = (short)h;
          l4[i] = (short)f2bf(f - bf2f(h));
        }
        *(bf16x4*)&bufBh[(size_t)bp * 256 + ob] = h4;
        *(bf16x4*)&bufBl[(size_t)bp * 256 + ob] = l4;
      }
  }
  grid.sync();

  // ======================= P2: conv + offsets + sampling + K/V GEMM ========
  {
    auto Xs  = (short (*)[3][34][264])(SM);            // [2][3][34][264]
    auto XsH = (short (*)[264])(SM + 107712);
    auto XsL = (short (*)[264])(SM + 124608);
    auto red = (float (*)[32][2])(SM + 141504);        // [4][32][2]
    auto crd = (float2*)(SM + 142528);
    const int b  = bid & 7;
    const int y0 = bid >> 3;
    const int bp0 = (b * 32 + y0) * 32;

    // phase 0: one-shot staging
    {
      bf16x8 v[12];
#pragma unroll
      for (int i = 0; i < 12; ++i) {
        int e = t + 512 * i;
        int oct = e & 31;
        int x   = (e >> 5) & 31;
        int rr  = e >> 10;
        int hl  = rr / 3, r = rr % 3;
        int yy  = y0 + r - 1;
        bf16x8 val = {};
        if (yy >= 0 && yy < 32) {
          const short* src = hl ? bufBl : bufBh;
          val = *(const bf16x8*)&src[((size_t)((b * 32 + yy) * 32 + x)) * 256 + oct * 8];
        }
        v[i] = val;
      }
#pragma unroll
      for (int i = 0; i < 12; ++i) {
        int e = t + 512 * i;
        int oct = e & 31;
        int x   = (e >> 5) & 31;
        int rr  = e >> 10;
        int hl  = rr / 3, r = rr % 3;
        *(bf16x8*)&Xs[hl][r][x + 1][oct * 8] = v[i];
      }
      if (t < 384) {
        int oct  = t & 31;
        int colw = (t >> 5) & 1;
        int rr   = t >> 6;
        int hl   = rr / 3, r = rr % 3;
        bf16x8 zz = {};
        *(bf16x8*)&Xs[hl][r][colw ? 33 : 0][oct * 8] = zz;
      }
    }
    __syncthreads();

    // phase 1: conv3x3, c0-split across wave-halves
    const int chh = w >> 2;
    const int ow  = w & 3;
    const int o0c = ow * 32;
    f32x4 acc[2][2] = {};
#pragma unroll
    for (int c0s = 0; c0s < 4; ++c0s) {
      const int c0 = chh * 128 + c0s * 32;
      const int c0abs = chh * 4 + c0s;
#pragma unroll
      for (int tap = 0; tap < 9; ++tap) {
        const int ky = tap / 3, kx = tap % 3;
        bf16x8 afr[2];
#pragma unroll
        for (int m = 0; m < 2; ++m)
          afr[m] = *(const bf16x8*)&wb[((((tap * 8 + (ow * 2 + m)) * 8 + c0abs) * 64
                                         + lane) * 8)];
#pragma unroll
        for (int nt = 0; nt < 2; ++nt) {
          int hc = nt * 16 + ln + kx;
          bf16x8 bh = *(const bf16x8*)&Xs[0][ky][hc][c0 + qd * 8];
          bf16x8 bl = *(const bf16x8*)&Xs[1][ky][hc][c0 + qd * 8];
#pragma unroll
          for (int m = 0; m < 2; ++m) {
            acc[m][nt] = __builtin_amdgcn_mfma_f32_16x16x32_bf16(afr[m], bh, acc[m][nt], 0, 0, 0);
            acc[m][nt] = __builtin_amdgcn_mfma_f32_16x16x32_bf16(afr[m], bl, acc[m][nt], 0, 0, 0);
          }
        }
      }
    }

    float* ps = (float*)&XsH[0][0];
    if (w >= 4) {
#pragma unroll
      for (int m = 0; m < 2; ++m)
#pragma unroll
        for (int nt = 0; nt < 2; ++nt)
          *(f32x4*)&ps[(((w - 4) * 64 + lane) * 4 + m * 2 + nt) * 4] = acc[m][nt];
    }
    __syncthreads();

    // phase 2: offset head -> coords
    if (w < 4) {
      float ps0[2] = {0.f, 0.f}, ps1[2] = {0.f, 0.f};
#pragma unroll
      for (int m = 0; m < 2; ++m)
#pragma unroll
        for (int nt = 0; nt < 2; ++nt) {
          f32x4 p = *(const f32x4*)&ps[((w * 64 + lane) * 4 + m * 2 + nt) * 4];
          acc[m][nt] += p;
        }
#pragma unroll
      for (int m = 0; m < 2; ++m)
#pragma unroll
        for (int i = 0; i < 4; ++i) {
          int o = o0c + m * 16 + qd * 4 + i;
          float bo = boff1[o];
          float w2a = Woff2[o], w2b = Woff2[128 + o];
#pragma unroll
          for (int nt = 0; nt < 2; ++nt) {
            float h = fmaxf(acc[m][nt][i] + bo, 0.f);
            ps0[nt] += w2a * h;
            ps1[nt] += w2b * h;
          }
        }
#pragma unroll
      for (int msk = 16; msk < 64; msk <<= 1) {
        ps0[0] += __shfl_xor(ps0[0], msk, 64);
        ps0[1] += __shfl_xor(ps0[1], msk, 64);
        ps1[0] += __shfl_xor(ps1[0], msk, 64);
        ps1[1] += __shfl_xor(ps1[1], msk, 64);
      }
      if (qd == 0) {
#pragma unroll
        for (int nt = 0; nt < 2; ++nt) {
          red[w][nt * 16 + ln][0] = ps0[nt];
          red[w][nt * 16 + ln][1] = ps1[nt];
        }
      }
    }
    __syncthreads();
    if (t < 32) {
      float c0s = (red[0][t][0] + red[1][t][0]) + (red[2][t][0] + red[3][t][0]) + boff2[0];
      float c1s = (red[0][t][1] + red[1][t][1]) + (red[2][t][1] + red[3][t][1]) + boff2[1];
      float gx = -1.f + 2.f * (float)t / 31.f;
      float gy = -1.f + 2.f * (float)y0 / 31.f;
      float vx = gx + 0.1f * c0s;
      float vy = gy + 0.1f * c1s;
      float px = fminf(fmaxf((vx + 1.f) * 0.5f * 31.f, 0.f), 31.f);
      float py = fminf(fmaxf((vy + 1.f) * 0.5f * 31.f, 0.f), 31.f);
      crd[t] = make_float2(px, py);
    }
    __syncthreads();

    // phase 3: sampling + K/V GEMM
#pragma unroll
    for (int it = 0; it < 2; ++it) {
      int e = t + 512 * it;
      int oct = e & 31, row = e >> 5;
      float2 cd = crd[row];
      float x0f = floorf(cd.x), y0f = floorf(cd.y);
      float wx = cd.x - x0f, wy = cd.y - y0f;
      int x0 = (int)x0f, y0i = (int)y0f;
      int x1 = min(x0 + 1, 31), y1 = min(y0i + 1, 31);
      float w00 = (1.f - wx) * (1.f - wy), w01 = wx * (1.f - wy);
      float w10 = (1.f - wx) * wy,         w11 = wx * wy;
      const float* r00 = &kvT[((size_t)(b * 1024 + y0i * 32 + x0)) * 256 + oct * 8];
      const float* r01 = &kvT[((size_t)(b * 1024 + y0i * 32 + x1)) * 256 + oct * 8];
      const float* r10 = &kvT[((size_t)(b * 1024 + y1 * 32 + x0)) * 256 + oct * 8];
      const float* r11 = &kvT[((size_t)(b * 1024 + y1 * 32 + x1)) * 256 + oct * 8];
      float4 a00 = *(const float4*)r00, b00 = *(const float4*)(r00 + 4);
      float4 a01 = *(const float4*)r01, b01 = *(const float4*)(r01 + 4);
      float4 a10 = *(const float4*)r10, b10 = *(const float4*)(r10 + 4);
      float4 a11 = *(const float4*)r11, b11 = *(const float4*)(r11 + 4);
      float v[8];
      v[0] = a00.x * w00 + a01.x * w01 + a10.x * w10 + a11.x * w11;
      v[1] = a00.y * w00 + a01.y * w01 + a10.y * w10 + a11.y * w11;
      v[2] = a00.z * w00 + a01.z * w01 + a10.z * w10 + a11.z * w11;
      v[3] = a00.w * w00 + a01.w * w01 + a10.w * w10 + a11.w * w11;
      v[4] = b00.x * w00 + b01.x * w01 + b10.x * w10 + b11.x * w11;
      v[5] = b00.y * w00 + b01.y * w01 + b10.y * w10 + b11.y * w11;
      v[6] = b00.z * w00 + b01.z * w01 + b10.z * w10 + b11.z * w11;
      v[7] = b00.w * w00 + b01.w * w01 + b10.w * w10 + b11.w * w11;
      bf16x8 h8, l8;
#pragma unroll
      for (int j = 0; j < 8; ++j) {
        unsigned short h = f2bf(v[j]);
        h8[j] = (short)h;
        l8[j] = (short)f2bf(v[j] - bf2f(h));
      }
      *(bf16x8*)&XsH[row][oct * 8] = h8;
      *(bf16x8*)&XsL[row][oct * 8] = l8;
    }
    __syncthreads();

    const int mat  = w >> 2;
    const short* WAh = WH + (mat ? 131072 : 65536);
    const short* WAl = WL + (mat ? 131072 : 65536);
    const int om4 = (w & 3) * 4;

    f32x4 acg[4][2] = {};
#pragma unroll
    for (int k0 = 0; k0 < 256; k0 += 32) {
      const int k0s = k0 >> 5;
      bf16x8 Bh[2], Bl[2];
#pragma unroll
      for (int nt = 0; nt < 2; ++nt) {
        Bh[nt] = *(const bf16x8*)&XsH[nt * 16 + ln][k0 + qd * 8];
        Bl[nt] = *(const bf16x8*)&XsL[nt * 16 + ln][k0 + qd * 8];
      }
#pragma unroll
      for (int mt = 0; mt < 4; ++mt) {
        size_t wi = ((size_t)(((om4 + mt) * 8 + k0s) * 64 + lane)) * 8;
        bf16x8 Ah = *(const bf16x8*)&WAh[wi];
        bf16x8 Al = *(const bf16x8*)&WAl[wi];
#pragma unroll
        for (int nt = 0; nt < 2; ++nt) {
          acg[mt][nt] = __builtin_amdgcn_mfma_f32_16x16x32_bf16(Ah, Bh[nt], acg[mt][nt], 0, 0, 0);
          acg[mt][nt] = __builtin_amdgcn_mfma_f32_16x16x32_bf16(Ah, Bl[nt], acg[mt][nt], 0, 0, 0);
          acg[mt][nt] = __builtin_amdgcn_mfma_f32_16x16x32_bf16(Al, Bh[nt], acg[mt][nt], 0, 0, 0);
        }
      }
    }

#pragma unroll
    for (int mt = 0; mt < 4; ++mt)
#pragma unroll
      for (int nt = 0; nt < 2; ++nt) {
        int p  = bp0 + nt * 16 + ln;
        int pl = p & 1023;
        int jt = pl >> 6, jl = pl & 63;
#pragma unroll
        for (int i = 0; i < 4; ++i) {
          int oc = (w & 3) * 64 + mt * 16 + qd * 4 + i;
          unsigned short val = f2bf(acg[mt][nt][i]);
          int bhead = b * 8 + (oc >> 5), d = oc & 31;
          if (mat == 0) {
            int cd2 = (d >> 3) ^ ((jl >> 2) & 3);
            kt[((((size_t)(bhead * 16 + jt)) * 64 + jl) * 4 + cd2) * 8 + (d & 7)] = (short)val;
          } else {
            int jjs = ((jl & 15) << 2) | (jl >> 4);     // sigma
            int cj = (jjs >> 3) ^ (d & 7);
            vt[((((size_t)(bhead * 16 + jt)) * 32 + d) * 8 + cj) * 8 + (jjs & 7)] = (short)val;
          }
        }
      }
  }
  grid.sync();

  // ======================= P3: flash attention =======================
  // 256 blocks; each = old block pair (bh, qp) & (bh, qp+4) sharing K/V stage.
  {
    auto Ks = (short (*)[2048])(SM);            // [2][2048]
    auto Vs = (short (*)[2048])(SM + 8192);     // [2][2048]
    auto P  = (short (*)[32][72])(SM + 16384);  // [8][32][72]
    const int b    = bid & 7;
    const int rem2 = bid >> 3;           // 0..31
    const int h    = rem2 & 7;
    const int qp   = rem2 >> 3;          // 0..3
    const int bh   = b * 8 + h;
    const int qce  = qp + 4 * (w >> 2);  // qc 0..7
    const int qbase = qce * 128 + (w & 3) * 16;

    const short* ktb = kt + (size_t)bh * 32768;
    const short* vtb = vt + (size_t)bh * 32768;

    bf16x8 aq[2];
    aq[0] = *(const bf16x8*)&qt[((size_t)(bh * 1024 + qbase + ln)) * 32 + qd * 8];
    aq[1] = *(const bf16x8*)&qt[((size_t)(bh * 1024 + qbase + 64 + ln)) * 32 + qd * 8];

    f32x4 acc[2][2] = {};
    float lacc[2][4] = {};
    const f32x4 zero = {0.f, 0.f, 0.f, 0.f};

    // staging: waves 0-3 fill Ks, waves 4-7 fill Vs (one copy each)
    const int sgw   = w & 3;
    const int stoff = sgw * 512 + lane * 8;
    const int ldoff = sgw * 512;

    if (w < 4) async_copy16(&ktb[stoff], &Ks[0][ldoff]);
    else       async_copy16(&vtb[stoff], &Vs[0][ldoff]);
    __syncthreads();

    for (int jt = 0; jt < 16; ++jt) {
      const int cur = jt & 1, nxt = cur ^ 1;
      if (jt < 15) {
        if (w < 4) async_copy16(&ktb[(jt + 1) * 2048 + stoff], &Ks[nxt][ldoff]);
        else       async_copy16(&vtb[(jt + 1) * 2048 + stoff], &Vs[nxt][ldoff]);
      }

      bf16x8 bk[4], bv[2][2];
#pragma unroll
      for (int kk = 0; kk < 4; ++kk)
        bk[kk] = *(const bf16x8*)&Ks[cur][((kk * 16 + ln) * 4 + (qd ^ ((ln >> 2) & 3))) * 8];
#pragma unroll
      for (int kc = 0; kc < 2; ++kc)
#pragma unroll
        for (int ds = 0; ds < 2; ++ds)
          bv[kc][ds] = *(const bf16x8*)&Vs[cur][((ds * 16 + ln) * 8 + ((kc * 4 + qd) ^ (ln & 7))) * 8];

#pragma unroll
      for (int qf = 0; qf < 2; ++qf) {
        f32x4 s[4];
        __builtin_amdgcn_s_setprio(1);
#pragma unroll
        for (int kk = 0; kk < 4; ++kk)
          s[kk] = __builtin_amdgcn_mfma_f32_16x16x32_bf16(aq[qf], bk[kk], zero, 0, 0, 0);
        __builtin_amdgcn_s_setprio(0);

#pragma unroll
        for (int i = 0; i < 4; ++i) {
          float p0 = __builtin_amdgcn_exp2f(s[0][i]);
          float p1 = __builtin_amdgcn_exp2f(s[1][i]);
          float p2 = __builtin_amdgcn_exp2f(s[2][i]);
          float p3 = __builtin_amdgcn_exp2f(s[3][i]);
          s[0][i] = p0; s[1][i] = p1; s[2][i] = p2; s[3][i] = p3;
          lacc[qf][i] += (p0 + p1) + (p2 + p3);
        }
#pragma unroll
        for (int i = 0; i < 4; ++i) {
          bf16x4 p4;
#pragma unroll
          for (int kk = 0; kk < 4; ++kk) p4[kk] = (short)f2bf_fast(s[kk][i]);
          *(bf16x4*)&P[w][qf * 16 + qd * 4 + i][4 * ln] = p4;
        }
        __builtin_amdgcn_s_setprio(1);
#pragma unroll
        for (int kc = 0; kc < 2; ++kc) {
          bf16x8 ap = *(const bf16x8*)&P[w][qf * 16 + ln][kc * 32 + qd * 8];
#pragma unroll
          for (int ds = 0; ds < 2; ++ds)
            acc[qf][ds] = __builtin_amdgcn_mfma_f32_16x16x32_bf16(ap, bv[kc][ds], acc[qf][ds], 0, 0, 0);
        }
        __builtin_amdgcn_s_setprio(0);
      }

      __syncthreads();
    }

    const int bb = bh >> 3, hh2 = bh & 7;
#pragma unroll
    for (int qf = 0; qf < 2; ++qf)
#pragma unroll
      for (int i = 0; i < 4; ++i) {
        float l = lacc[qf][i];
        l += __shfl_xor(l, 1, 64);
        l += __shfl_xor(l, 2, 64);
        l += __shfl_xor(l, 4, 64);
        l += __shfl_xor(l, 8, 64);
        float inv = 1.f / l;
        int qrow = qbase + qf * 64 + qd * 4 + i;
#pragma unroll
        for (int ds = 0; ds < 2; ++ds) {
          float v = acc[qf][ds][i] * inv;
          unsigned short hv = f2bf(v);
          size_t idx = ((size_t)(bb * 1024 + qrow)) * 256 + hh2 * 32 + ds * 16 + ln;
          bufBh[idx] = (short)hv;
          bufBl[idx] = (short)f2bf(v - bf2f(hv));
        }
      }
  }
  grid.sync();

  // ======================= P4: output GEMM =======================
  // X tile (ao hi/lo) staged once, shared by both M-halves.
  {
    auto XsH = (short (*)[264])(SM);
    auto XsL = (short (*)[264])(SM + 16896);
    const int bp0 = bid * 32;
    const short* Wh = WH + 196608;      // packed Wout hi
    const short* Wl = WL + 196608;

#pragma unroll
    for (int it = 0; it < 2; ++it) {
      int e = t + 512 * it;
      int oct = e & 31, row = e >> 5;
      bf16x8 vh = *(const bf16x8*)&bufBh[((size_t)(bp0 + row)) * 256 + oct * 8];
      bf16x8 vl = *(const bf16x8*)&bufBl[((size_t)(bp0 + row)) * 256 + oct * 8];
      *(bf16x8*)&XsH[row][oct * 8] = vh;
      *(bf16x8*)&XsL[row][oct * 8] = vl;
    }
    __syncthreads();

    const int mh = w >> 2, ww = w & 3;
    const int mb = mh * 8 + ww * 2;
    f32x4 acc[2][2] = {};
#pragma unroll
    for (int k0 = 0; k0 < 256; k0 += 32) {
      const int k0s = k0 >> 5;
      bf16x8 Ah[2], Al[2], Bh[2], Bl[2];
#pragma unroll
      for (int mt = 0; mt < 2; ++mt) {
        size_t wi = ((size_t)(((mb + mt) * 8 + k0s) * 64 + lane)) * 8;
        Ah[mt] = *(const bf16x8*)&Wh[wi];
        Al[mt] = *(const bf16x8*)&Wl[wi];
      }
#pragma unroll
      for (int nt = 0; nt < 2; ++nt) {
        Bh[nt] = *(const bf16x8*)&XsH[nt * 16 + ln][k0 + qd * 8];
        Bl[nt] = *(const bf16x8*)&XsL[nt * 16 + ln][k0 + qd * 8];
      }
#pragma unroll
      for (int mt = 0; mt < 2; ++mt)
#pragma unroll
        for (int nt = 0; nt < 2; ++nt) {
          acc[mt][nt] = __builtin_amdgcn_mfma_f32_16x16x32_bf16(Ah[mt], Bh[nt], acc[mt][nt], 0, 0, 0);
          acc[mt][nt] = __builtin_amdgcn_mfma_f32_16x16x32_bf16(Ah[mt], Bl[nt], acc[mt][nt], 0, 0, 0);
          acc[mt][nt] = __builtin_amdgcn_mfma_f32_16x16x32_bf16(Al[mt], Bh[nt], acc[mt][nt], 0, 0, 0);
        }
    }

    const int om = mh * 128 + ww * 32;
#pragma unroll
    for (int mt = 0; mt < 2; ++mt)
#pragma unroll
      for (int i = 0; i < 4; ++i) {
        int o = om + mt * 16 + qd * 4 + i;
        float bo = bout[o];
#pragma unroll
        for (int nt = 0; nt < 2; ++nt) {
          int bp = bp0 + nt * 16 + ln;
          int b = bp >> 10, p = bp & 1023;
          out[((size_t)(b * 256 + o)) * HW_ + p] = acc[mt][nt][i] + bo;
        }
      }
  }
}

// ---------------------------------------------------------------------------
extern "C" void kernel_launch(void* const* d_in, const int* in_sizes, int n_in,
                              void* d_out, int out_size, void* d_ws, size_t ws_size,
                              hipStream_t stream)
{
  const float* query_map = (const float*)d_in[0];
  const float* kv_map    = (const float*)d_in[1];
  const float* Wq        = (const float*)d_in[2];
  const float* Wk        = (const float*)d_in[3];
  const float* Wv        = (const float*)d_in[4];
  const float* Woff1     = (const float*)d_in[5];
  const float* boff1     = (const float*)d_in[6];
  const float* Woff2     = (const float*)d_in[7];
  const float* boff2     = (const float*)d_in[8];
  const float* Wout      = (const float*)d_in[9];
  const float* bout      = (const float*)d_in[10];
  float* out = (float*)d_out;
  char* base = (char*)d_ws;

  const size_t MB = 1u << 20;
  short* qt     = (short*)(base + 1 * MB);     // 4 MB (bh,p,d) pre-scaled
  short* kt     = (short*)(base + 5 * MB);     // 4 MB tiled+swizzled
  short* vt     = (short*)(base + 9 * MB);     // 4 MB tiled+swizzled
  short* bufBh  = (short*)(base + 13 * MB);    // 4 MB q hi -> ao hi
  short* bufBl  = (short*)(base + 17 * MB);    // 4 MB q lo -> ao lo
  short* wb     = (short*)(base + 21 * MB);    // 576 KB conv weights (packed)
  short* WH     = (short*)(base + 22 * MB);    // 512 KB [Wq|Wk|Wv|Wout] packed hi
  short* WL     = (short*)(base + 23 * MB);    // 512 KB lo
  float* kvT    = (float*)(base + 24 * MB);    // 8 MB kv_map (b,p,c) f32

  void* ka[] = {
    (void*)&kv_map, (void*)&Wq, (void*)&Wk, (void*)&Wv, (void*)&Wout,
    (void*)&Woff1, (void*)&boff1, (void*)&Woff2, (void*)&boff2,
    (void*)&bout, (void*)&query_map, (void*)&out,
    (void*)&WH, (void*)&WL, (void*)&wb, (void*)&kvT, (void*)&qt,
    (void*)&kt, (void*)&vt, (void*)&bufBh, (void*)&bufBl,
  };
  hipLaunchCooperativeKernel((void*)mega, dim3(256), dim3(512), ka, 0, stream);
}

// Round 9
// 159.918 us; speedup vs baseline: 1.8936x; 1.8936x over previous
//
#include <hip/hip_runtime.h>

#define HW_ 1024

typedef __attribute__((ext_vector_type(8))) short bf16x8;   // 8 bf16 = 4 VGPRs
typedef __attribute__((ext_vector_type(4))) short bf16x4;   // 8 B
typedef __attribute__((ext_vector_type(4))) float f32x4;

__device__ inline unsigned short f2bf(float f) {            // RNE f32->bf16
  unsigned int u = __float_as_uint(f);
  u += 0x7FFF + ((u >> 16) & 1);
  return (unsigned short)(u >> 16);
}
__device__ inline unsigned short f2bf_fast(float f) {       // ties-away (2 ops)
  return (unsigned short)((__float_as_uint(f) + 0x8000u) >> 16);
}
__device__ inline float bf2f(unsigned short h) {
  return __uint_as_float(((unsigned int)h) << 16);
}
__device__ inline void async_copy16(const void* g, void* l) {
  __builtin_amdgcn_global_load_lds(
      (const __attribute__((address_space(1))) unsigned int*)g,
      (__attribute__((address_space(3))) unsigned int*)l, 16, 0, 0);
}

// ---------------------------------------------------------------------------
// prep (grid 800): one-time marshalling (R7 verbatim).
//   [0,256) kvT transpose; [256,512) wsplit packed; [512,800) conv wb packed.
// ---------------------------------------------------------------------------
__global__ __launch_bounds__(256) void prep(
    const float* __restrict__ kv,
    const float* __restrict__ Wq, const float* __restrict__ Wk,
    const float* __restrict__ Wv, const float* __restrict__ Wo,
    const float* __restrict__ Woff1,
    short* __restrict__ WH, short* __restrict__ WL, short* __restrict__ wb,
    float* __restrict__ kvT)
{
  __shared__ float T[256][33];
  const int bid = blockIdx.x, t = threadIdx.x;

  if (bid < 256) {                      // ---- kvT transpose ----
    int b = bid >> 5, p0 = (bid & 31) * 32;
    int pp = t & 31, cg = t >> 5;
#pragma unroll
    for (int i = 0; i < 32; ++i) {
      int c = cg * 32 + i;
      T[c][pp] = kv[((size_t)(b * 256 + c)) * HW_ + p0 + pp];
    }
    __syncthreads();
#pragma unroll
    for (int r = 0; r < 8; ++r) {
      int e = t + 256 * r;
      int c4 = (e & 63) * 4, pp2 = e >> 6;
      float4 v4;
      v4.x = T[c4 + 0][pp2];
      v4.y = T[c4 + 1][pp2];
      v4.z = T[c4 + 2][pp2];
      v4.w = T[c4 + 3][pp2];
      *(float4*)&kvT[((size_t)(b * 1024 + p0 + pp2)) * 256 + c4] = v4;
    }
  } else if (bid < 512) {               // ---- wsplit, all packed ----
    int b2 = bid - 256;
    int mat = b2 >> 6;                  // 0..3 = Wq,Wk,Wv,Wout
    int loc = (b2 & 63) * 1024 + t * 4;
    const float* W = (mat == 0) ? Wq : (mat == 1) ? Wk : (mat == 2) ? Wv : Wo;
    float4 f4 = *(const float4*)&W[loc];
    float f[4] = {f4.x, f4.y, f4.z, f4.w};
    bf16x4 h4, l4;
#pragma unroll
    for (int j = 0; j < 4; ++j) {
      unsigned short h = f2bf(f[j]);
      h4[j] = (short)h;
      l4[j] = (short)f2bf(f[j] - bf2f(h));
    }
    int r = loc >> 8, c = loc & 255;    // 4 consecutive c in one 8-group
    int mtile = r >> 4, k0s = c >> 5;
    int lane_ = ((c >> 3) & 3) * 16 + (r & 15);
    int pidx = (((mtile * 8 + k0s) * 64 + lane_) * 8) + (c & 7);
    *(bf16x4*)&WH[mat * 65536 + pidx] = h4;
    *(bf16x4*)&WL[mat * 65536 + pidx] = l4;
  } else {                              // ---- conv weight repack (packed) ----
    int e0 = (bid - 512) * 1024 + t * 4;
    int c = e0 & 255;
    int o = (e0 >> 8) & 127;
    int tap = e0 >> 15;
    bf16x4 h4;
#pragma unroll
    for (int j = 0; j < 4; ++j)
      h4[j] = (short)f2bf(Woff1[((size_t)(o * 256 + c + j)) * 9 + tap]);
    int otile = o >> 4, c0s = c >> 5;
    int lane_ = ((c >> 3) & 3) * 16 + (o & 15);
    int widx = ((((tap * 8 + otile) * 8 + c0s) * 64 + lane_) * 8) + (c & 7);
    *(bf16x4*)&wb[widx] = h4;
  }
}

// ---------------------------------------------------------------------------
// qgemm: Q projection. 512 threads, grid 256: ONE X-stage (32p x 256c hi/lo)
// shared by BOTH M-halves (R7 staged it twice across blockIdx.y). Packed-Wq
// A-frags. Same wave/CU count as R7; X f32 reads + split VALU halved.
// ---------------------------------------------------------------------------
__global__ __launch_bounds__(512) void qgemm(
    const short* __restrict__ WH, const short* __restrict__ WL,
    const float* __restrict__ Xf,
    short* __restrict__ Yt, short* __restrict__ Yh2, short* __restrict__ Yl2)
{
  __shared__ short Bsh[32][264];
  __shared__ short Bsl[32][264];
  const int t    = threadIdx.x;
  const int w    = t >> 6;              // 0..7
  const int lane = t & 63;
  const int ln   = lane & 15;
  const int qd   = lane >> 4;
  const int bp0  = blockIdx.x * 32;
  const int bB   = bp0 >> 10, p0l = bp0 & 1023;

  {                                     // one-shot stage + split
    int pp = t & 31, cs = t >> 5;       // cs 0..15 -> 16 c's each
    float fv[16];
#pragma unroll
    for (int j = 0; j < 16; ++j)
      fv[j] = Xf[((size_t)(bB * 256 + cs * 16 + j)) * HW_ + p0l + pp];
#pragma unroll
    for (int g = 0; g < 4; ++g) {
      bf16x4 h4, l4;
#pragma unroll
      for (int j = 0; j < 4; ++j) {
        float f = fv[g * 4 + j];
        unsigned short h = f2bf(f);
        h4[j] = (short)h;
        l4[j] = (short)f2bf(f - bf2f(h));
      }
      *(bf16x4*)&Bsh[pp][cs * 16 + g * 4] = h4;
      *(bf16x4*)&Bsl[pp][cs * 16 + g * 4] = l4;
    }
  }
  __syncthreads();

  const int mh = w >> 2, ww = w & 3;
  const int mb = mh * 8 + ww * 2;
  f32x4 acc[2][2] = {};
#pragma unroll
  for (int k0 = 0; k0 < 256; k0 += 32) {
    const int k0s = k0 >> 5;
    bf16x8 Ah[2], Al[2], Bh[2], Bl[2];
#pragma unroll
    for (int mt = 0; mt < 2; ++mt) {    // packed: dense 1 KB wave-read
      size_t wi = ((size_t)(((mb + mt) * 8 + k0s) * 64 + lane)) * 8;
      Ah[mt] = *(const bf16x8*)&WH[wi];
      Al[mt] = *(const bf16x8*)&WL[wi];
    }
#pragma unroll
    for (int nt = 0; nt < 2; ++nt) {
      Bh[nt] = *(const bf16x8*)&Bsh[nt * 16 + ln][k0 + qd * 8];
      Bl[nt] = *(const bf16x8*)&Bsl[nt * 16 + ln][k0 + qd * 8];
    }
#pragma unroll
    for (int mt = 0; mt < 2; ++mt)
#pragma unroll
      for (int nt = 0; nt < 2; ++nt) {
        acc[mt][nt] = __builtin_amdgcn_mfma_f32_16x16x32_bf16(Ah[mt], Bh[nt], acc[mt][nt], 0, 0, 0);
        acc[mt][nt] = __builtin_amdgcn_mfma_f32_16x16x32_bf16(Ah[mt], Bl[nt], acc[mt][nt], 0, 0, 0);
        acc[mt][nt] = __builtin_amdgcn_mfma_f32_16x16x32_bf16(Al[mt], Bh[nt], acc[mt][nt], 0, 0, 0);
      }
  }

  const int om = mh * 128 + ww * 32;
  const float sc = 0.25506063286f;      // (1/sqrt32)*log2(e)
#pragma unroll
  for (int mt = 0; mt < 2; ++mt)
#pragma unroll
    for (int nt = 0; nt < 2; ++nt) {
      int bp = bp0 + nt * 16 + ln;
      int b = bp >> 10, p = bp & 1023;
#pragma unroll
      for (int i = 0; i < 4; ++i) {
        int o = om + mt * 16 + qd * 4 + i;
        int h = o >> 5, d = o & 31;
        Yt[(((size_t)(b * 8 + h)) * 1024 + p) * 32 + d] = (short)f2bf(acc[mt][nt][i] * sc);
      }
      int ob = om + mt * 16 + qd * 4;
      bf16x4 h4, l4;
#pragma unroll
      for (int i = 0; i < 4; ++i) {
        float f = acc[mt][nt][i];
        unsigned short h = f2bf(f);
        h4[i] = (short)h;
        l4[i] = (short)f2bf(f - bf2f(h));
      }
      *(bf16x4*)&Yh2[(size_t)bp * 256 + ob] = h4;
      *(bf16x4*)&Yl2[(size_t)bp * 256 + ob] = l4;
    }
}

// ---------------------------------------------------------------------------
// convkv (R7 verbatim): one-shot staging + c0-split conv + offset head +
// sampling + K/V GEMM, packed weights. grid 256, 512 thr, LDS 139.5 KB.
// ---------------------------------------------------------------------------
__global__ __launch_bounds__(512) void convkv(
    const short* __restrict__ wb, const float* __restrict__ bias,
    const float* __restrict__ W2, const float* __restrict__ b2,
    const short* __restrict__ xh, const short* __restrict__ xl,
    const float* __restrict__ kvT,
    const short* __restrict__ WH, const short* __restrict__ WL,
    short* __restrict__ kt, short* __restrict__ vt)
{
  __shared__ short Xs[2][3][34][264];
  __shared__ short XsH[32][264];
  __shared__ short XsL[32][264];
  __shared__ float red[4][32][2];
  __shared__ float2 crd[32];
  const int id   = blockIdx.x;          // 256
  const int b    = id & 7;
  const int y0   = id >> 3;
  const int t    = threadIdx.x;
  const int w    = t >> 6;
  const int lane = t & 63;
  const int ln   = lane & 15;
  const int qd   = lane >> 4;
  const int bp0  = (b * 32 + y0) * 32;

  // phase 0: one-shot staging
  {
    bf16x8 v[12];
#pragma unroll
    for (int i = 0; i < 12; ++i) {
      int e = t + 512 * i;
      int oct = e & 31;
      int x   = (e >> 5) & 31;
      int rr  = e >> 10;
      int hl  = rr / 3, r = rr % 3;
      int yy  = y0 + r - 1;
      bf16x8 val = {};
      if (yy >= 0 && yy < 32) {
        const short* src = hl ? xl : xh;
        val = *(const bf16x8*)&src[((size_t)((b * 32 + yy) * 32 + x)) * 256 + oct * 8];
      }
      v[i] = val;
    }
#pragma unroll
    for (int i = 0; i < 12; ++i) {
      int e = t + 512 * i;
      int oct = e & 31;
      int x   = (e >> 5) & 31;
      int rr  = e >> 10;
      int hl  = rr / 3, r = rr % 3;
      *(bf16x8*)&Xs[hl][r][x + 1][oct * 8] = v[i];
    }
    if (t < 384) {
      int oct  = t & 31;
      int colw = (t >> 5) & 1;
      int rr   = t >> 6;
      int hl   = rr / 3, r = rr % 3;
      bf16x8 zz = {};
      *(bf16x8*)&Xs[hl][r][colw ? 33 : 0][oct * 8] = zz;
    }
  }
  __syncthreads();

  // phase 1: conv3x3, c0-split across wave-halves
  const int chh = w >> 2;
  const int ow  = w & 3;
  const int o0c = ow * 32;
  f32x4 acc[2][2] = {};
#pragma unroll
  for (int c0s = 0; c0s < 4; ++c0s) {
    const int c0 = chh * 128 + c0s * 32;
    const int c0abs = chh * 4 + c0s;
#pragma unroll
    for (int tap = 0; tap < 9; ++tap) {
      const int ky = tap / 3, kx = tap % 3;
      bf16x8 afr[2];
#pragma unroll
      for (int m = 0; m < 2; ++m)
        afr[m] = *(const bf16x8*)&wb[((((tap * 8 + (ow * 2 + m)) * 8 + c0abs) * 64
                                       + lane) * 8)];
#pragma unroll
      for (int nt = 0; nt < 2; ++nt) {
        int hc = nt * 16 + ln + kx;
        bf16x8 bh = *(const bf16x8*)&Xs[0][ky][hc][c0 + qd * 8];
        bf16x8 bl = *(const bf16x8*)&Xs[1][ky][hc][c0 + qd * 8];
#pragma unroll
        for (int m = 0; m < 2; ++m) {
          acc[m][nt] = __builtin_amdgcn_mfma_f32_16x16x32_bf16(afr[m], bh, acc[m][nt], 0, 0, 0);
          acc[m][nt] = __builtin_amdgcn_mfma_f32_16x16x32_bf16(afr[m], bl, acc[m][nt], 0, 0, 0);
        }
      }
    }
  }

  float* ps = (float*)&XsH[0][0];
  if (w >= 4) {
#pragma unroll
    for (int m = 0; m < 2; ++m)
#pragma unroll
      for (int nt = 0; nt < 2; ++nt)
        *(f32x4*)&ps[(((w - 4) * 64 + lane) * 4 + m * 2 + nt) * 4] = acc[m][nt];
  }
  __syncthreads();

  // phase 2: offset head -> coords
  if (w < 4) {
    float ps0[2] = {0.f, 0.f}, ps1[2] = {0.f, 0.f};
#pragma unroll
    for (int m = 0; m < 2; ++m)
#pragma unroll
      for (int nt = 0; nt < 2; ++nt) {
        f32x4 p = *(const f32x4*)&ps[((w * 64 + lane) * 4 + m * 2 + nt) * 4];
        acc[m][nt] += p;
      }
#pragma unroll
    for (int m = 0; m < 2; ++m)
#pragma unroll
      for (int i = 0; i < 4; ++i) {
        int o = o0c + m * 16 + qd * 4 + i;
        float bo = bias[o];
        float w2a = W2[o], w2b = W2[128 + o];
#pragma unroll
        for (int nt = 0; nt < 2; ++nt) {
          float h = fmaxf(acc[m][nt][i] + bo, 0.f);
          ps0[nt] += w2a * h;
          ps1[nt] += w2b * h;
        }
      }
#pragma unroll
    for (int msk = 16; msk < 64; msk <<= 1) {
      ps0[0] += __shfl_xor(ps0[0], msk, 64);
      ps0[1] += __shfl_xor(ps0[1], msk, 64);
      ps1[0] += __shfl_xor(ps1[0], msk, 64);
      ps1[1] += __shfl_xor(ps1[1], msk, 64);
    }
    if (qd == 0) {
#pragma unroll
      for (int nt = 0; nt < 2; ++nt) {
        red[w][nt * 16 + ln][0] = ps0[nt];
        red[w][nt * 16 + ln][1] = ps1[nt];
      }
    }
  }
  __syncthreads();
  if (t < 32) {
    float c0s = (red[0][t][0] + red[1][t][0]) + (red[2][t][0] + red[3][t][0]) + b2[0];
    float c1s = (red[0][t][1] + red[1][t][1]) + (red[2][t][1] + red[3][t][1]) + b2[1];
    float gx = -1.f + 2.f * (float)t / 31.f;
    float gy = -1.f + 2.f * (float)y0 / 31.f;
    float vx = gx + 0.1f * c0s;
    float vy = gy + 0.1f * c1s;
    float px = fminf(fmaxf((vx + 1.f) * 0.5f * 31.f, 0.f), 31.f);
    float py = fminf(fmaxf((vy + 1.f) * 0.5f * 31.f, 0.f), 31.f);
    crd[t] = make_float2(px, py);
  }
  __syncthreads();

  // phase 3: sampling + K/V GEMM
#pragma unroll
  for (int it = 0; it < 2; ++it) {
    int e = t + 512 * it;
    int oct = e & 31, row = e >> 5;
    float2 cd = crd[row];
    float x0f = floorf(cd.x), y0f = floorf(cd.y);
    float wx = cd.x - x0f, wy = cd.y - y0f;
    int x0 = (int)x0f, y0i = (int)y0f;
    int x1 = min(x0 + 1, 31), y1 = min(y0i + 1, 31);
    float w00 = (1.f - wx) * (1.f - wy), w01 = wx * (1.f - wy);
    float w10 = (1.f - wx) * wy,         w11 = wx * wy;
    const float* r00 = &kvT[((size_t)(b * 1024 + y0i * 32 + x0)) * 256 + oct * 8];
    const float* r01 = &kvT[((size_t)(b * 1024 + y0i * 32 + x1)) * 256 + oct * 8];
    const float* r10 = &kvT[((size_t)(b * 1024 + y1 * 32 + x0)) * 256 + oct * 8];
    const float* r11 = &kvT[((size_t)(b * 1024 + y1 * 32 + x1)) * 256 + oct * 8];
    float4 a00 = *(const float4*)r00, b00 = *(const float4*)(r00 + 4);
    float4 a01 = *(const float4*)r01, b01 = *(const float4*)(r01 + 4);
    float4 a10 = *(const float4*)r10, b10 = *(const float4*)(r10 + 4);
    float4 a11 = *(const float4*)r11, b11 = *(const float4*)(r11 + 4);
    float v[8];
    v[0] = a00.x * w00 + a01.x * w01 + a10.x * w10 + a11.x * w11;
    v[1] = a00.y * w00 + a01.y * w01 + a10.y * w10 + a11.y * w11;
    v[2] = a00.z * w00 + a01.z * w01 + a10.z * w10 + a11.z * w11;
    v[3] = a00.w * w00 + a01.w * w01 + a10.w * w10 + a11.w * w11;
    v[4] = b00.x * w00 + b01.x * w01 + b10.x * w10 + b11.x * w11;
    v[5] = b00.y * w00 + b01.y * w01 + b10.y * w10 + b11.y * w11;
    v[6] = b00.z * w00 + b01.z * w01 + b10.z * w10 + b11.z * w11;
    v[7] = b00.w * w00 + b01.w * w01 + b10.w * w10 + b11.w * w11;
    bf16x8 h8, l8;
#pragma unroll
    for (int j = 0; j < 8; ++j) {
      unsigned short h = f2bf(v[j]);
      h8[j] = (short)h;
      l8[j] = (short)f2bf(v[j] - bf2f(h));
    }
    *(bf16x8*)&XsH[row][oct * 8] = h8;
    *(bf16x8*)&XsL[row][oct * 8] = l8;
  }
  __syncthreads();

  const int mat  = w >> 2;
  const short* WAh = WH + (mat ? 131072 : 65536);
  const short* WAl = WL + (mat ? 131072 : 65536);
  const int om4 = (w & 3) * 4;

  f32x4 acg[4][2] = {};
#pragma unroll
  for (int k0 = 0; k0 < 256; k0 += 32) {
    const int k0s = k0 >> 5;
    bf16x8 Bh[2], Bl[2];
#pragma unroll
    for (int nt = 0; nt < 2; ++nt) {
      Bh[nt] = *(const bf16x8*)&XsH[nt * 16 + ln][k0 + qd * 8];
      Bl[nt] = *(const bf16x8*)&XsL[nt * 16 + ln][k0 + qd * 8];
    }
#pragma unroll
    for (int mt = 0; mt < 4; ++mt) {
      size_t wi = ((size_t)(((om4 + mt) * 8 + k0s) * 64 + lane)) * 8;
      bf16x8 Ah = *(const bf16x8*)&WAh[wi];
      bf16x8 Al = *(const bf16x8*)&WAl[wi];
#pragma unroll
      for (int nt = 0; nt < 2; ++nt) {
        acg[mt][nt] = __builtin_amdgcn_mfma_f32_16x16x32_bf16(Ah, Bh[nt], acg[mt][nt], 0, 0, 0);
        acg[mt][nt] = __builtin_amdgcn_mfma_f32_16x16x32_bf16(Ah, Bl[nt], acg[mt][nt], 0, 0, 0);
        acg[mt][nt] = __builtin_amdgcn_mfma_f32_16x16x32_bf16(Al, Bh[nt], acg[mt][nt], 0, 0, 0);
      }
    }
  }

#pragma unroll
  for (int mt = 0; mt < 4; ++mt)
#pragma unroll
    for (int nt = 0; nt < 2; ++nt) {
      int p  = bp0 + nt * 16 + ln;
      int pl = p & 1023;
      int jt = pl >> 6, jl = pl & 63;
#pragma unroll
      for (int i = 0; i < 4; ++i) {
        int oc = (w & 3) * 64 + mt * 16 + qd * 4 + i;
        unsigned short val = f2bf(acg[mt][nt][i]);
        int bhead = b * 8 + (oc >> 5), d = oc & 31;
        if (mat == 0) {
          int cd2 = (d >> 3) ^ ((jl >> 2) & 3);
          kt[((((size_t)(bhead * 16 + jt)) * 64 + jl) * 4 + cd2) * 8 + (d & 7)] = (short)val;
        } else {
          int jjs = ((jl & 15) << 2) | (jl >> 4);       // sigma
          int cj = (jjs >> 3) ^ (d & 7);
          vt[((((size_t)(bhead * 16 + jt)) * 32 + d) * 8 + cj) * 8 + (jjs & 7)] = (short)val;
        }
      }
    }
}

// ---------------------------------------------------------------------------
// MFMA flash attention (R7 verbatim). grid 512, 256 thr, 2 q-frags/wave.
// ---------------------------------------------------------------------------
__global__ __launch_bounds__(256) void attn_mfma(
    const short* __restrict__ qt, const short* __restrict__ kt,
    const short* __restrict__ vt, short* __restrict__ aoh,
    short* __restrict__ aol)
{
  __shared__ __align__(16) short Ks[2][2048];
  __shared__ __align__(16) short Vs[2][2048];
  __shared__ __align__(16) short P[4][32][72];
  const int t    = threadIdx.x;
  const int w    = t >> 6;
  const int lane = t & 63;
  const int ln   = lane & 15;
  const int qd   = lane >> 4;
  const int id   = blockIdx.x;          // 512
  const int b    = id & 7;
  const int rem  = id >> 3;
  const int h    = rem & 7;
  const int qc   = rem >> 3;
  const int bh   = b * 8 + h;
  const int qbase = qc * 128 + w * 16;

  const short* ktb = kt + (size_t)bh * 32768;
  const short* vtb = vt + (size_t)bh * 32768;

  bf16x8 aq[2];
  aq[0] = *(const bf16x8*)&qt[((size_t)(bh * 1024 + qbase + ln)) * 32 + qd * 8];
  aq[1] = *(const bf16x8*)&qt[((size_t)(bh * 1024 + qbase + 64 + ln)) * 32 + qd * 8];

  f32x4 acc[2][2] = {};
  float lacc[2][4] = {};
  const f32x4 zero = {0.f, 0.f, 0.f, 0.f};

  const int stoff = w * 512 + lane * 8;
  const int ldoff = w * 512;

  async_copy16(&ktb[stoff], &Ks[0][ldoff]);
  async_copy16(&vtb[stoff], &Vs[0][ldoff]);
  __syncthreads();

  for (int jt = 0; jt < 16; ++jt) {
    const int cur = jt & 1, nxt = cur ^ 1;
    if (jt < 15) {
      async_copy16(&ktb[(jt + 1) * 2048 + stoff], &Ks[nxt][ldoff]);
      async_copy16(&vtb[(jt + 1) * 2048 + stoff], &Vs[nxt][ldoff]);
    }

    bf16x8 bk[4], bv[2][2];
#pragma unroll
    for (int kk = 0; kk < 4; ++kk)
      bk[kk] = *(const bf16x8*)&Ks[cur][((kk * 16 + ln) * 4 + (qd ^ ((ln >> 2) & 3))) * 8];
#pragma unroll
    for (int kc = 0; kc < 2; ++kc)
#pragma unroll
      for (int ds = 0; ds < 2; ++ds)
        bv[kc][ds] = *(const bf16x8*)&Vs[cur][((ds * 16 + ln) * 8 + ((kc * 4 + qd) ^ (ln & 7))) * 8];

#pragma unroll
    for (int qf = 0; qf < 2; ++qf) {
      f32x4 s[4];
      __builtin_amdgcn_s_setprio(1);
#pragma unroll
      for (int kk = 0; kk < 4; ++kk)
        s[kk] = __builtin_amdgcn_mfma_f32_16x16x32_bf16(aq[qf], bk[kk], zero, 0, 0, 0);
      __builtin_amdgcn_s_setprio(0);

#pragma unroll
      for (int i = 0; i < 4; ++i) {
        float p0 = __builtin_amdgcn_exp2f(s[0][i]);
        float p1 = __builtin_amdgcn_exp2f(s[1][i]);
        float p2 = __builtin_amdgcn_exp2f(s[2][i]);
        float p3 = __builtin_amdgcn_exp2f(s[3][i]);
        s[0][i] = p0; s[1][i] = p1; s[2][i] = p2; s[3][i] = p3;
        lacc[qf][i] += (p0 + p1) + (p2 + p3);
      }
#pragma unroll
      for (int i = 0; i < 4; ++i) {
        bf16x4 p4;
#pragma unroll
        for (int kk = 0; kk < 4; ++kk) p4[kk] = (short)f2bf_fast(s[kk][i]);
        *(bf16x4*)&P[w][qf * 16 + qd * 4 + i][4 * ln] = p4;
      }
      __builtin_amdgcn_s_setprio(1);
#pragma unroll
      for (int kc = 0; kc < 2; ++kc) {
        bf16x8 ap = *(const bf16x8*)&P[w][qf * 16 + ln][kc * 32 + qd * 8];
#pragma unroll
        for (int ds = 0; ds < 2; ++ds)
          acc[qf][ds] = __builtin_amdgcn_mfma_f32_16x16x32_bf16(ap, bv[kc][ds], acc[qf][ds], 0, 0, 0);
      }
      __builtin_amdgcn_s_setprio(0);
    }

    __syncthreads();
  }

  const int bb = bh >> 3, hh2 = bh & 7;
#pragma unroll
  for (int qf = 0; qf < 2; ++qf)
#pragma unroll
    for (int i = 0; i < 4; ++i) {
      float l = lacc[qf][i];
      l += __shfl_xor(l, 1, 64);
      l += __shfl_xor(l, 2, 64);
      l += __shfl_xor(l, 4, 64);
      l += __shfl_xor(l, 8, 64);
      float inv = 1.f / l;
      int qrow = qbase + qf * 64 + qd * 4 + i;
#pragma unroll
      for (int ds = 0; ds < 2; ++ds) {
        float v = acc[qf][ds][i] * inv;
        unsigned short hv = f2bf(v);
        size_t idx = ((size_t)(bb * 1024 + qrow)) * 256 + hh2 * 32 + ds * 16 + ln;
        aoh[idx] = (short)hv;
        aol[idx] = (short)f2bf(v - bf2f(hv));
      }
    }
}

// ---------------------------------------------------------------------------
// Output GEMM (Wout): 512 threads, grid 256 — X tile staged ONCE, shared by
// both M-halves (R7 staged twice). Packed A-frags.
// ---------------------------------------------------------------------------
__global__ __launch_bounds__(512) void gemm_out(
    const short* __restrict__ Wh, const short* __restrict__ Wl,
    const short* __restrict__ Xh, const short* __restrict__ Xl,
    const float* __restrict__ bias, float* __restrict__ Yf)
{
  __shared__ short XsH[32][264];
  __shared__ short XsL[32][264];
  const int t    = threadIdx.x;
  const int w    = t >> 6;              // 0..7
  const int lane = t & 63;
  const int ln   = lane & 15;
  const int qd   = lane >> 4;
  const int bp0  = blockIdx.x * 32;

#pragma unroll
  for (int it = 0; it < 2; ++it) {      // stage X tile: dense 16B loads
    int e = t + 512 * it;
    int oct = e & 31, row = e >> 5;
    bf16x8 vh = *(const bf16x8*)&Xh[((size_t)(bp0 + row)) * 256 + oct * 8];
    bf16x8 vl = *(const bf16x8*)&Xl[((size_t)(bp0 + row)) * 256 + oct * 8];
    *(bf16x8*)&XsH[row][oct * 8] = vh;
    *(bf16x8*)&XsL[row][oct * 8] = vl;
  }
  __syncthreads();

  const int mh = w >> 2, ww = w & 3;
  const int mb = mh * 8 + ww * 2;
  f32x4 acc[2][2] = {};
#pragma unroll
  for (int k0 = 0; k0 < 256; k0 += 32) {
    const int k0s = k0 >> 5;
    bf16x8 Ah[2], Al[2], Bh[2], Bl[2];
#pragma unroll
    for (int mt = 0; mt < 2; ++mt) {    // packed: dense 1 KB wave-read
      size_t wi = ((size_t)(((mb + mt) * 8 + k0s) * 64 + lane)) * 8;
      Ah[mt] = *(const bf16x8*)&Wh[wi];
      Al[mt] = *(const bf16x8*)&Wl[wi];
    }
#pragma unroll
    for (int nt = 0; nt < 2; ++nt) {
      Bh[nt] = *(const bf16x8*)&XsH[nt * 16 + ln][k0 + qd * 8];
      Bl[nt] = *(const bf16x8*)&XsL[nt * 16 + ln][k0 + qd * 8];
    }
#pragma unroll
    for (int mt = 0; mt < 2; ++mt)
#pragma unroll
      for (int nt = 0; nt < 2; ++nt) {
        acc[mt][nt] = __builtin_amdgcn_mfma_f32_16x16x32_bf16(Ah[mt], Bh[nt], acc[mt][nt], 0, 0, 0);
        acc[mt][nt] = __builtin_amdgcn_mfma_f32_16x16x32_bf16(Ah[mt], Bl[nt], acc[mt][nt], 0, 0, 0);
        acc[mt][nt] = __builtin_amdgcn_mfma_f32_16x16x32_bf16(Al[mt], Bh[nt], acc[mt][nt], 0, 0, 0);
      }
  }

  const int om = mh * 128 + ww * 32;
#pragma unroll
  for (int mt = 0; mt < 2; ++mt)
#pragma unroll
    for (int i = 0; i < 4; ++i) {
      int o = om + mt * 16 + qd * 4 + i;
      float bo = bias[o];
#pragma unroll
      for (int nt = 0; nt < 2; ++nt) {
        int bp = bp0 + nt * 16 + ln;
        int b = bp >> 10, p = bp & 1023;
        Yf[((size_t)(b * 256 + o)) * HW_ + p] = acc[mt][nt][i] + bo;
      }
    }
}

// ---------------------------------------------------------------------------
extern "C" void kernel_launch(void* const* d_in, const int* in_sizes, int n_in,
                              void* d_out, int out_size, void* d_ws, size_t ws_size,
                              hipStream_t stream)
{
  const float* query_map = (const float*)d_in[0];
  const float* kv_map    = (const float*)d_in[1];
  const float* Wq        = (const float*)d_in[2];
  const float* Wk        = (const float*)d_in[3];
  const float* Wv        = (const float*)d_in[4];
  const float* Woff1     = (const float*)d_in[5];
  const float* boff1     = (const float*)d_in[6];
  const float* Woff2     = (const float*)d_in[7];
  const float* boff2     = (const float*)d_in[8];
  const float* Wout      = (const float*)d_in[9];
  const float* bout      = (const float*)d_in[10];
  float* out = (float*)d_out;
  char* base = (char*)d_ws;

  const size_t MB = 1u << 20;
  short* qt     = (short*)(base + 1 * MB);     // 4 MB (bh,p,d) pre-scaled
  short* kt     = (short*)(base + 5 * MB);     // 4 MB tiled+swizzled
  short* vt     = (short*)(base + 9 * MB);     // 4 MB tiled+swizzled
  short* bufBh  = (short*)(base + 13 * MB);    // 4 MB q hi -> ao hi
  short* bufBl  = (short*)(base + 17 * MB);    // 4 MB q lo -> ao lo
  short* wb     = (short*)(base + 21 * MB);    // 576 KB conv weights (packed)
  short* WH     = (short*)(base + 22 * MB);    // 512 KB [Wq|Wk|Wv|Wout] packed hi
  short* WL     = (short*)(base + 23 * MB);    // 512 KB lo
  float* kvT    = (float*)(base + 24 * MB);    // 8 MB kv_map (b,p,c) f32

  prep<<<dim3(800), dim3(256), 0, stream>>>(kv_map, Wq, Wk, Wv, Wout, Woff1,
                                            WH, WL, wb, kvT);
  qgemm<<<dim3(256), dim3(512), 0, stream>>>(WH, WL, query_map,
                                             qt, bufBh, bufBl);
  convkv<<<dim3(256), dim3(512), 0, stream>>>(wb, boff1, Woff2, boff2,
                                              bufBh, bufBl, kvT, WH, WL, kt, vt);
  attn_mfma<<<dim3(512), dim3(256), 0, stream>>>(qt, kt, vt, bufBh, bufBl);
  gemm_out<<<dim3(256), dim3(512), 0, stream>>>(WH + 196608, WL + 196608,
                                                bufBh, bufBl, bout, out);
}

// Round 10
// 157.475 us; speedup vs baseline: 1.9230x; 1.0155x over previous
//
#include <hip/hip_runtime.h>

#define HW_ 1024

typedef __attribute__((ext_vector_type(8))) short bf16x8;   // 8 bf16 = 4 VGPRs
typedef __attribute__((ext_vector_type(4))) short bf16x4;   // 8 B
typedef __attribute__((ext_vector_type(4))) float f32x4;

__device__ inline unsigned short f2bf(float f) {            // RNE f32->bf16
  unsigned int u = __float_as_uint(f);
  u += 0x7FFF + ((u >> 16) & 1);
  return (unsigned short)(u >> 16);
}
__device__ inline unsigned short f2bf_fast(float f) {       // ties-away (2 ops)
  return (unsigned short)((__float_as_uint(f) + 0x8000u) >> 16);
}
__device__ inline float bf2f(unsigned short h) {
  return __uint_as_float(((unsigned int)h) << 16);
}
__device__ inline void async_copy16(const void* g, void* l) {
  __builtin_amdgcn_global_load_lds(
      (const __attribute__((address_space(1))) unsigned int*)g,
      (__attribute__((address_space(3))) unsigned int*)l, 16, 0, 0);
}

// ---------------------------------------------------------------------------
// prep (grid 800): one-time marshalling (R9 verbatim).
//   [0,256) kvT transpose; [256,512) wsplit packed; [512,800) conv wb packed.
// ---------------------------------------------------------------------------
__global__ __launch_bounds__(256) void prep(
    const float* __restrict__ kv,
    const float* __restrict__ Wq, const float* __restrict__ Wk,
    const float* __restrict__ Wv, const float* __restrict__ Wo,
    const float* __restrict__ Woff1,
    short* __restrict__ WH, short* __restrict__ WL, short* __restrict__ wb,
    float* __restrict__ kvT)
{
  __shared__ float T[256][33];
  const int bid = blockIdx.x, t = threadIdx.x;

  if (bid < 256) {                      // ---- kvT transpose ----
    int b = bid >> 5, p0 = (bid & 31) * 32;
    int pp = t & 31, cg = t >> 5;
#pragma unroll
    for (int i = 0; i < 32; ++i) {
      int c = cg * 32 + i;
      T[c][pp] = kv[((size_t)(b * 256 + c)) * HW_ + p0 + pp];
    }
    __syncthreads();
#pragma unroll
    for (int r = 0; r < 8; ++r) {
      int e = t + 256 * r;
      int c4 = (e & 63) * 4, pp2 = e >> 6;
      float4 v4;
      v4.x = T[c4 + 0][pp2];
      v4.y = T[c4 + 1][pp2];
      v4.z = T[c4 + 2][pp2];
      v4.w = T[c4 + 3][pp2];
      *(float4*)&kvT[((size_t)(b * 1024 + p0 + pp2)) * 256 + c4] = v4;
    }
  } else if (bid < 512) {               // ---- wsplit, all packed ----
    int b2 = bid - 256;
    int mat = b2 >> 6;                  // 0..3 = Wq,Wk,Wv,Wout
    int loc = (b2 & 63) * 1024 + t * 4;
    const float* W = (mat == 0) ? Wq : (mat == 1) ? Wk : (mat == 2) ? Wv : Wo;
    float4 f4 = *(const float4*)&W[loc];
    float f[4] = {f4.x, f4.y, f4.z, f4.w};
    bf16x4 h4, l4;
#pragma unroll
    for (int j = 0; j < 4; ++j) {
      unsigned short h = f2bf(f[j]);
      h4[j] = (short)h;
      l4[j] = (short)f2bf(f[j] - bf2f(h));
    }
    int r = loc >> 8, c = loc & 255;    // 4 consecutive c in one 8-group
    int mtile = r >> 4, k0s = c >> 5;
    int lane_ = ((c >> 3) & 3) * 16 + (r & 15);
    int pidx = (((mtile * 8 + k0s) * 64 + lane_) * 8) + (c & 7);
    *(bf16x4*)&WH[mat * 65536 + pidx] = h4;
    *(bf16x4*)&WL[mat * 65536 + pidx] = l4;
  } else {                              // ---- conv weight repack (packed) ----
    int e0 = (bid - 512) * 1024 + t * 4;
    int c = e0 & 255;
    int o = (e0 >> 8) & 127;
    int tap = e0 >> 15;
    bf16x4 h4;
#pragma unroll
    for (int j = 0; j < 4; ++j)
      h4[j] = (short)f2bf(Woff1[((size_t)(o * 256 + c + j)) * 9 + tap]);
    int otile = o >> 4, c0s = c >> 5;
    int lane_ = ((c >> 3) & 3) * 16 + (o & 15);
    int widx = ((((tap * 8 + otile) * 8 + c0s) * 64 + lane_) * 8) + (c & 7);
    *(bf16x4*)&wb[widx] = h4;
  }
}

// ---------------------------------------------------------------------------
// qgemm (R9 verbatim): 512 thr, grid 256, one shared X-stage, packed Wq.
// ---------------------------------------------------------------------------
__global__ __launch_bounds__(512) void qgemm(
    const short* __restrict__ WH, const short* __restrict__ WL,
    const float* __restrict__ Xf,
    short* __restrict__ Yt, short* __restrict__ Yh2, short* __restrict__ Yl2)
{
  __shared__ short Bsh[32][264];
  __shared__ short Bsl[32][264];
  const int t    = threadIdx.x;
  const int w    = t >> 6;              // 0..7
  const int lane = t & 63;
  const int ln   = lane & 15;
  const int qd   = lane >> 4;
  const int bp0  = blockIdx.x * 32;
  const int bB   = bp0 >> 10, p0l = bp0 & 1023;

  {                                     // one-shot stage + split
    int pp = t & 31, cs = t >> 5;       // cs 0..15 -> 16 c's each
    float fv[16];
#pragma unroll
    for (int j = 0; j < 16; ++j)
      fv[j] = Xf[((size_t)(bB * 256 + cs * 16 + j)) * HW_ + p0l + pp];
#pragma unroll
    for (int g = 0; g < 4; ++g) {
      bf16x4 h4, l4;
#pragma unroll
      for (int j = 0; j < 4; ++j) {
        float f = fv[g * 4 + j];
        unsigned short h = f2bf(f);
        h4[j] = (short)h;
        l4[j] = (short)f2bf(f - bf2f(h));
      }
      *(bf16x4*)&Bsh[pp][cs * 16 + g * 4] = h4;
      *(bf16x4*)&Bsl[pp][cs * 16 + g * 4] = l4;
    }
  }
  __syncthreads();

  const int mh = w >> 2, ww = w & 3;
  const int mb = mh * 8 + ww * 2;
  f32x4 acc[2][2] = {};
#pragma unroll
  for (int k0 = 0; k0 < 256; k0 += 32) {
    const int k0s = k0 >> 5;
    bf16x8 Ah[2], Al[2], Bh[2], Bl[2];
#pragma unroll
    for (int mt = 0; mt < 2; ++mt) {    // packed: dense 1 KB wave-read
      size_t wi = ((size_t)(((mb + mt) * 8 + k0s) * 64 + lane)) * 8;
      Ah[mt] = *(const bf16x8*)&WH[wi];
      Al[mt] = *(const bf16x8*)&WL[wi];
    }
#pragma unroll
    for (int nt = 0; nt < 2; ++nt) {
      Bh[nt] = *(const bf16x8*)&Bsh[nt * 16 + ln][k0 + qd * 8];
      Bl[nt] = *(const bf16x8*)&Bsl[nt * 16 + ln][k0 + qd * 8];
    }
#pragma unroll
    for (int mt = 0; mt < 2; ++mt)
#pragma unroll
      for (int nt = 0; nt < 2; ++nt) {
        acc[mt][nt] = __builtin_amdgcn_mfma_f32_16x16x32_bf16(Ah[mt], Bh[nt], acc[mt][nt], 0, 0, 0);
        acc[mt][nt] = __builtin_amdgcn_mfma_f32_16x16x32_bf16(Ah[mt], Bl[nt], acc[mt][nt], 0, 0, 0);
        acc[mt][nt] = __builtin_amdgcn_mfma_f32_16x16x32_bf16(Al[mt], Bh[nt], acc[mt][nt], 0, 0, 0);
      }
  }

  const int om = mh * 128 + ww * 32;
  const float sc = 0.25506063286f;      // (1/sqrt32)*log2(e)
#pragma unroll
  for (int mt = 0; mt < 2; ++mt)
#pragma unroll
    for (int nt = 0; nt < 2; ++nt) {
      int bp = bp0 + nt * 16 + ln;
      int b = bp >> 10, p = bp & 1023;
#pragma unroll
      for (int i = 0; i < 4; ++i) {
        int o = om + mt * 16 + qd * 4 + i;
        int h = o >> 5, d = o & 31;
        Yt[(((size_t)(b * 8 + h)) * 1024 + p) * 32 + d] = (short)f2bf(acc[mt][nt][i] * sc);
      }
      int ob = om + mt * 16 + qd * 4;
      bf16x4 h4, l4;
#pragma unroll
      for (int i = 0; i < 4; ++i) {
        float f = acc[mt][nt][i];
        unsigned short h = f2bf(f);
        h4[i] = (short)h;
        l4[i] = (short)f2bf(f - bf2f(h));
      }
      *(bf16x4*)&Yh2[(size_t)bp * 256 + ob] = h4;
      *(bf16x4*)&Yl2[(size_t)bp * 256 + ob] = l4;
    }
}

// ---------------------------------------------------------------------------
// convkv (R9 verbatim): one-shot staging + c0-split conv + offset head +
// sampling + K/V GEMM, packed weights. grid 256, 512 thr, LDS 139.5 KB.
// ---------------------------------------------------------------------------
__global__ __launch_bounds__(512) void convkv(
    const short* __restrict__ wb, const float* __restrict__ bias,
    const float* __restrict__ W2, const float* __restrict__ b2,
    const short* __restrict__ xh, const short* __restrict__ xl,
    const float* __restrict__ kvT,
    const short* __restrict__ WH, const short* __restrict__ WL,
    short* __restrict__ kt, short* __restrict__ vt)
{
  __shared__ short Xs[2][3][34][264];
  __shared__ short XsH[32][264];
  __shared__ short XsL[32][264];
  __shared__ float red[4][32][2];
  __shared__ float2 crd[32];
  const int id   = blockIdx.x;          // 256
  const int b    = id & 7;
  const int y0   = id >> 3;
  const int t    = threadIdx.x;
  const int w    = t >> 6;
  const int lane = t & 63;
  const int ln   = lane & 15;
  const int qd   = lane >> 4;
  const int bp0  = (b * 32 + y0) * 32;

  // phase 0: one-shot staging
  {
    bf16x8 v[12];
#pragma unroll
    for (int i = 0; i < 12; ++i) {
      int e = t + 512 * i;
      int oct = e & 31;
      int x   = (e >> 5) & 31;
      int rr  = e >> 10;
      int hl  = rr / 3, r = rr % 3;
      int yy  = y0 + r - 1;
      bf16x8 val = {};
      if (yy >= 0 && yy < 32) {
        const short* src = hl ? xl : xh;
        val = *(const bf16x8*)&src[((size_t)((b * 32 + yy) * 32 + x)) * 256 + oct * 8];
      }
      v[i] = val;
    }
#pragma unroll
    for (int i = 0; i < 12; ++i) {
      int e = t + 512 * i;
      int oct = e & 31;
      int x   = (e >> 5) & 31;
      int rr  = e >> 10;
      int hl  = rr / 3, r = rr % 3;
      *(bf16x8*)&Xs[hl][r][x + 1][oct * 8] = v[i];
    }
    if (t < 384) {
      int oct  = t & 31;
      int colw = (t >> 5) & 1;
      int rr   = t >> 6;
      int hl   = rr / 3, r = rr % 3;
      bf16x8 zz = {};
      *(bf16x8*)&Xs[hl][r][colw ? 33 : 0][oct * 8] = zz;
    }
  }
  __syncthreads();

  // phase 1: conv3x3, c0-split across wave-halves
  const int chh = w >> 2;
  const int ow  = w & 3;
  const int o0c = ow * 32;
  f32x4 acc[2][2] = {};
#pragma unroll
  for (int c0s = 0; c0s < 4; ++c0s) {
    const int c0 = chh * 128 + c0s * 32;
    const int c0abs = chh * 4 + c0s;
#pragma unroll
    for (int tap = 0; tap < 9; ++tap) {
      const int ky = tap / 3, kx = tap % 3;
      bf16x8 afr[2];
#pragma unroll
      for (int m = 0; m < 2; ++m)
        afr[m] = *(const bf16x8*)&wb[((((tap * 8 + (ow * 2 + m)) * 8 + c0abs) * 64
                                       + lane) * 8)];
#pragma unroll
      for (int nt = 0; nt < 2; ++nt) {
        int hc = nt * 16 + ln + kx;
        bf16x8 bh = *(const bf16x8*)&Xs[0][ky][hc][c0 + qd * 8];
        bf16x8 bl = *(const bf16x8*)&Xs[1][ky][hc][c0 + qd * 8];
#pragma unroll
        for (int m = 0; m < 2; ++m) {
          acc[m][nt] = __builtin_amdgcn_mfma_f32_16x16x32_bf16(afr[m], bh, acc[m][nt], 0, 0, 0);
          acc[m][nt] = __builtin_amdgcn_mfma_f32_16x16x32_bf16(afr[m], bl, acc[m][nt], 0, 0, 0);
        }
      }
    }
  }

  float* ps = (float*)&XsH[0][0];
  if (w >= 4) {
#pragma unroll
    for (int m = 0; m < 2; ++m)
#pragma unroll
      for (int nt = 0; nt < 2; ++nt)
        *(f32x4*)&ps[(((w - 4) * 64 + lane) * 4 + m * 2 + nt) * 4] = acc[m][nt];
  }
  __syncthreads();

  // phase 2: offset head -> coords
  if (w < 4) {
    float ps0[2] = {0.f, 0.f}, ps1[2] = {0.f, 0.f};
#pragma unroll
    for (int m = 0; m < 2; ++m)
#pragma unroll
      for (int nt = 0; nt < 2; ++nt) {
        f32x4 p = *(const f32x4*)&ps[((w * 64 + lane) * 4 + m * 2 + nt) * 4];
        acc[m][nt] += p;
      }
#pragma unroll
    for (int m = 0; m < 2; ++m)
#pragma unroll
      for (int i = 0; i < 4; ++i) {
        int o = o0c + m * 16 + qd * 4 + i;
        float bo = bias[o];
        float w2a = W2[o], w2b = W2[128 + o];
#pragma unroll
        for (int nt = 0; nt < 2; ++nt) {
          float h = fmaxf(acc[m][nt][i] + bo, 0.f);
          ps0[nt] += w2a * h;
          ps1[nt] += w2b * h;
        }
      }
#pragma unroll
    for (int msk = 16; msk < 64; msk <<= 1) {
      ps0[0] += __shfl_xor(ps0[0], msk, 64);
      ps0[1] += __shfl_xor(ps0[1], msk, 64);
      ps1[0] += __shfl_xor(ps1[0], msk, 64);
      ps1[1] += __shfl_xor(ps1[1], msk, 64);
    }
    if (qd == 0) {
#pragma unroll
      for (int nt = 0; nt < 2; ++nt) {
        red[w][nt * 16 + ln][0] = ps0[nt];
        red[w][nt * 16 + ln][1] = ps1[nt];
      }
    }
  }
  __syncthreads();
  if (t < 32) {
    float c0s = (red[0][t][0] + red[1][t][0]) + (red[2][t][0] + red[3][t][0]) + b2[0];
    float c1s = (red[0][t][1] + red[1][t][1]) + (red[2][t][1] + red[3][t][1]) + b2[1];
    float gx = -1.f + 2.f * (float)t / 31.f;
    float gy = -1.f + 2.f * (float)y0 / 31.f;
    float vx = gx + 0.1f * c0s;
    float vy = gy + 0.1f * c1s;
    float px = fminf(fmaxf((vx + 1.f) * 0.5f * 31.f, 0.f), 31.f);
    float py = fminf(fmaxf((vy + 1.f) * 0.5f * 31.f, 0.f), 31.f);
    crd[t] = make_float2(px, py);
  }
  __syncthreads();

  // phase 3: sampling + K/V GEMM
#pragma unroll
  for (int it = 0; it < 2; ++it) {
    int e = t + 512 * it;
    int oct = e & 31, row = e >> 5;
    float2 cd = crd[row];
    float x0f = floorf(cd.x), y0f = floorf(cd.y);
    float wx = cd.x - x0f, wy = cd.y - y0f;
    int x0 = (int)x0f, y0i = (int)y0f;
    int x1 = min(x0 + 1, 31), y1 = min(y0i + 1, 31);
    float w00 = (1.f - wx) * (1.f - wy), w01 = wx * (1.f - wy);
    float w10 = (1.f - wx) * wy,         w11 = wx * wy;
    const float* r00 = &kvT[((size_t)(b * 1024 + y0i * 32 + x0)) * 256 + oct * 8];
    const float* r01 = &kvT[((size_t)(b * 1024 + y0i * 32 + x1)) * 256 + oct * 8];
    const float* r10 = &kvT[((size_t)(b * 1024 + y1 * 32 + x0)) * 256 + oct * 8];
    const float* r11 = &kvT[((size_t)(b * 1024 + y1 * 32 + x1)) * 256 + oct * 8];
    float4 a00 = *(const float4*)r00, b00 = *(const float4*)(r00 + 4);
    float4 a01 = *(const float4*)r01, b01 = *(const float4*)(r01 + 4);
    float4 a10 = *(const float4*)r10, b10 = *(const float4*)(r10 + 4);
    float4 a11 = *(const float4*)r11, b11 = *(const float4*)(r11 + 4);
    float v[8];
    v[0] = a00.x * w00 + a01.x * w01 + a10.x * w10 + a11.x * w11;
    v[1] = a00.y * w00 + a01.y * w01 + a10.y * w10 + a11.y * w11;
    v[2] = a00.z * w00 + a01.z * w01 + a10.z * w10 + a11.z * w11;
    v[3] = a00.w * w00 + a01.w * w01 + a10.w * w10 + a11.w * w11;
    v[4] = b00.x * w00 + b01.x * w01 + b10.x * w10 + b11.x * w11;
    v[5] = b00.y * w00 + b01.y * w01 + b10.y * w10 + b11.y * w11;
    v[6] = b00.z * w00 + b01.z * w01 + b10.z * w10 + b11.z * w11;
    v[7] = b00.w * w00 + b01.w * w01 + b10.w * w10 + b11.w * w11;
    bf16x8 h8, l8;
#pragma unroll
    for (int j = 0; j < 8; ++j) {
      unsigned short h = f2bf(v[j]);
      h8[j] = (short)h;
      l8[j] = (short)f2bf(v[j] - bf2f(h));
    }
    *(bf16x8*)&XsH[row][oct * 8] = h8;
    *(bf16x8*)&XsL[row][oct * 8] = l8;
  }
  __syncthreads();

  const int mat  = w >> 2;
  const short* WAh = WH + (mat ? 131072 : 65536);
  const short* WAl = WL + (mat ? 131072 : 65536);
  const int om4 = (w & 3) * 4;

  f32x4 acg[4][2] = {};
#pragma unroll
  for (int k0 = 0; k0 < 256; k0 += 32) {
    const int k0s = k0 >> 5;
    bf16x8 Bh[2], Bl[2];
#pragma unroll
    for (int nt = 0; nt < 2; ++nt) {
      Bh[nt] = *(const bf16x8*)&XsH[nt * 16 + ln][k0 + qd * 8];
      Bl[nt] = *(const bf16x8*)&XsL[nt * 16 + ln][k0 + qd * 8];
    }
#pragma unroll
    for (int mt = 0; mt < 4; ++mt) {
      size_t wi = ((size_t)(((om4 + mt) * 8 + k0s) * 64 + lane)) * 8;
      bf16x8 Ah = *(const bf16x8*)&WAh[wi];
      bf16x8 Al = *(const bf16x8*)&WAl[wi];
#pragma unroll
      for (int nt = 0; nt < 2; ++nt) {
        acg[mt][nt] = __builtin_amdgcn_mfma_f32_16x16x32_bf16(Ah, Bh[nt], acg[mt][nt], 0, 0, 0);
        acg[mt][nt] = __builtin_amdgcn_mfma_f32_16x16x32_bf16(Ah, Bl[nt], acg[mt][nt], 0, 0, 0);
        acg[mt][nt] = __builtin_amdgcn_mfma_f32_16x16x32_bf16(Al, Bh[nt], acg[mt][nt], 0, 0, 0);
      }
    }
  }

#pragma unroll
  for (int mt = 0; mt < 4; ++mt)
#pragma unroll
    for (int nt = 0; nt < 2; ++nt) {
      int p  = bp0 + nt * 16 + ln;
      int pl = p & 1023;
      int jt = pl >> 6, jl = pl & 63;
#pragma unroll
      for (int i = 0; i < 4; ++i) {
        int oc = (w & 3) * 64 + mt * 16 + qd * 4 + i;
        unsigned short val = f2bf(acg[mt][nt][i]);
        int bhead = b * 8 + (oc >> 5), d = oc & 31;
        if (mat == 0) {
          int cd2 = (d >> 3) ^ ((jl >> 2) & 3);
          kt[((((size_t)(bhead * 16 + jt)) * 64 + jl) * 4 + cd2) * 8 + (d & 7)] = (short)val;
        } else {
          int jjs = ((jl & 15) << 2) | (jl >> 4);       // sigma
          int cj = (jjs >> 3) ^ (d & 7);
          vt[((((size_t)(bhead * 16 + jt)) * 32 + d) * 8 + cj) * 8 + (jjs & 7)] = (short)val;
        }
      }
    }
}

// ---------------------------------------------------------------------------
// MFMA flash attention, PAIRED: grid 256 x 512 thr. Each block = the old
// (bh,qc)/(bh,qc+4) block pair sharing ONE K/V double-buffer (waves 0-3 stage
// K, 4-7 stage V; all 8 consume). kt/vt L2 traffic halves (64->32 MB); same
// 8 waves/CU occupancy. Structure = mega P3 (correctness-proven in R8).
// ---------------------------------------------------------------------------
__global__ __launch_bounds__(512) void attn_mfma(
    const short* __restrict__ qt, const short* __restrict__ kt,
    const short* __restrict__ vt, short* __restrict__ aoh,
    short* __restrict__ aol)
{
  __shared__ __align__(16) short Ks[2][2048];
  __shared__ __align__(16) short Vs[2][2048];
  __shared__ __align__(16) short P[8][32][72];
  const int t    = threadIdx.x;
  const int w    = t >> 6;              // 0..7
  const int lane = t & 63;
  const int ln   = lane & 15;
  const int qd   = lane >> 4;
  const int bid  = blockIdx.x;          // 256
  const int b    = bid & 7;
  const int rem2 = bid >> 3;            // 0..31
  const int h    = rem2 & 7;
  const int qp   = rem2 >> 3;           // 0..3
  const int bh   = b * 8 + h;
  const int qce  = qp + 4 * (w >> 2);   // qc: waves 0-3 -> qp, 4-7 -> qp+4
  const int qbase = qce * 128 + (w & 3) * 16;

  const short* ktb = kt + (size_t)bh * 32768;
  const short* vtb = vt + (size_t)bh * 32768;

  bf16x8 aq[2];
  aq[0] = *(const bf16x8*)&qt[((size_t)(bh * 1024 + qbase + ln)) * 32 + qd * 8];
  aq[1] = *(const bf16x8*)&qt[((size_t)(bh * 1024 + qbase + 64 + ln)) * 32 + qd * 8];

  f32x4 acc[2][2] = {};
  float lacc[2][4] = {};
  const f32x4 zero = {0.f, 0.f, 0.f, 0.f};

  const int sgw   = w & 3;
  const int stoff = sgw * 512 + lane * 8;
  const int ldoff = sgw * 512;

  if (w < 4) async_copy16(&ktb[stoff], &Ks[0][ldoff]);
  else       async_copy16(&vtb[stoff], &Vs[0][ldoff]);
  __syncthreads();

  for (int jt = 0; jt < 16; ++jt) {
    const int cur = jt & 1, nxt = cur ^ 1;
    if (jt < 15) {
      if (w < 4) async_copy16(&ktb[(jt + 1) * 2048 + stoff], &Ks[nxt][ldoff]);
      else       async_copy16(&vtb[(jt + 1) * 2048 + stoff], &Vs[nxt][ldoff]);
    }

    bf16x8 bk[4], bv[2][2];
#pragma unroll
    for (int kk = 0; kk < 4; ++kk)
      bk[kk] = *(const bf16x8*)&Ks[cur][((kk * 16 + ln) * 4 + (qd ^ ((ln >> 2) & 3))) * 8];
#pragma unroll
    for (int kc = 0; kc < 2; ++kc)
#pragma unroll
      for (int ds = 0; ds < 2; ++ds)
        bv[kc][ds] = *(const bf16x8*)&Vs[cur][((ds * 16 + ln) * 8 + ((kc * 4 + qd) ^ (ln & 7))) * 8];

#pragma unroll
    for (int qf = 0; qf < 2; ++qf) {
      f32x4 s[4];
      __builtin_amdgcn_s_setprio(1);
#pragma unroll
      for (int kk = 0; kk < 4; ++kk)
        s[kk] = __builtin_amdgcn_mfma_f32_16x16x32_bf16(aq[qf], bk[kk], zero, 0, 0, 0);
      __builtin_amdgcn_s_setprio(0);

#pragma unroll
      for (int i = 0; i < 4; ++i) {
        float p0 = __builtin_amdgcn_exp2f(s[0][i]);
        float p1 = __builtin_amdgcn_exp2f(s[1][i]);
        float p2 = __builtin_amdgcn_exp2f(s[2][i]);
        float p3 = __builtin_amdgcn_exp2f(s[3][i]);
        s[0][i] = p0; s[1][i] = p1; s[2][i] = p2; s[3][i] = p3;
        lacc[qf][i] += (p0 + p1) + (p2 + p3);
      }
#pragma unroll
      for (int i = 0; i < 4; ++i) {
        bf16x4 p4;
#pragma unroll
        for (int kk = 0; kk < 4; ++kk) p4[kk] = (short)f2bf_fast(s[kk][i]);
        *(bf16x4*)&P[w][qf * 16 + qd * 4 + i][4 * ln] = p4;
      }
      __builtin_amdgcn_s_setprio(1);
#pragma unroll
      for (int kc = 0; kc < 2; ++kc) {
        bf16x8 ap = *(const bf16x8*)&P[w][qf * 16 + ln][kc * 32 + qd * 8];
#pragma unroll
        for (int ds = 0; ds < 2; ++ds)
          acc[qf][ds] = __builtin_amdgcn_mfma_f32_16x16x32_bf16(ap, bv[kc][ds], acc[qf][ds], 0, 0, 0);
      }
      __builtin_amdgcn_s_setprio(0);
    }

    __syncthreads();
  }

  const int bb = bh >> 3, hh2 = bh & 7;
#pragma unroll
  for (int qf = 0; qf < 2; ++qf)
#pragma unroll
    for (int i = 0; i < 4; ++i) {
      float l = lacc[qf][i];
      l += __shfl_xor(l, 1, 64);
      l += __shfl_xor(l, 2, 64);
      l += __shfl_xor(l, 4, 64);
      l += __shfl_xor(l, 8, 64);
      float inv = 1.f / l;
      int qrow = qbase + qf * 64 + qd * 4 + i;
#pragma unroll
      for (int ds = 0; ds < 2; ++ds) {
        float v = acc[qf][ds][i] * inv;
        unsigned short hv = f2bf(v);
        size_t idx = ((size_t)(bb * 1024 + qrow)) * 256 + hh2 * 32 + ds * 16 + ln;
        aoh[idx] = (short)hv;
        aol[idx] = (short)f2bf(v - bf2f(hv));
      }
    }
}

// ---------------------------------------------------------------------------
// Output GEMM (R9 verbatim): 512 thr, grid 256, shared X tile, packed Wout.
// ---------------------------------------------------------------------------
__global__ __launch_bounds__(512) void gemm_out(
    const short* __restrict__ Wh, const short* __restrict__ Wl,
    const short* __restrict__ Xh, const short* __restrict__ Xl,
    const float* __restrict__ bias, float* __restrict__ Yf)
{
  __shared__ short XsH[32][264];
  __shared__ short XsL[32][264];
  const int t    = threadIdx.x;
  const int w    = t >> 6;              // 0..7
  const int lane = t & 63;
  const int ln   = lane & 15;
  const int qd   = lane >> 4;
  const int bp0  = blockIdx.x * 32;

#pragma unroll
  for (int it = 0; it < 2; ++it) {      // stage X tile: dense 16B loads
    int e = t + 512 * it;
    int oct = e & 31, row = e >> 5;
    bf16x8 vh = *(const bf16x8*)&Xh[((size_t)(bp0 + row)) * 256 + oct * 8];
    bf16x8 vl = *(const bf16x8*)&Xl[((size_t)(bp0 + row)) * 256 + oct * 8];
    *(bf16x8*)&XsH[row][oct * 8] = vh;
    *(bf16x8*)&XsL[row][oct * 8] = vl;
  }
  __syncthreads();

  const int mh = w >> 2, ww = w & 3;
  const int mb = mh * 8 + ww * 2;
  f32x4 acc[2][2] = {};
#pragma unroll
  for (int k0 = 0; k0 < 256; k0 += 32) {
    const int k0s = k0 >> 5;
    bf16x8 Ah[2], Al[2], Bh[2], Bl[2];
#pragma unroll
    for (int mt = 0; mt < 2; ++mt) {    // packed: dense 1 KB wave-read
      size_t wi = ((size_t)(((mb + mt) * 8 + k0s) * 64 + lane)) * 8;
      Ah[mt] = *(const bf16x8*)&Wh[wi];
      Al[mt] = *(const bf16x8*)&Wl[wi];
    }
#pragma unroll
    for (int nt = 0; nt < 2; ++nt) {
      Bh[nt] = *(const bf16x8*)&XsH[nt * 16 + ln][k0 + qd * 8];
      Bl[nt] = *(const bf16x8*)&XsL[nt * 16 + ln][k0 + qd * 8];
    }
#pragma unroll
    for (int mt = 0; mt < 2; ++mt)
#pragma unroll
      for (int nt = 0; nt < 2; ++nt) {
        acc[mt][nt] = __builtin_amdgcn_mfma_f32_16x16x32_bf16(Ah[mt], Bh[nt], acc[mt][nt], 0, 0, 0);
        acc[mt][nt] = __builtin_amdgcn_mfma_f32_16x16x32_bf16(Ah[mt], Bl[nt], acc[mt][nt], 0, 0, 0);
        acc[mt][nt] = __builtin_amdgcn_mfma_f32_16x16x32_bf16(Al[mt], Bh[nt], acc[mt][nt], 0, 0, 0);
      }
  }

  const int om = mh * 128 + ww * 32;
#pragma unroll
  for (int mt = 0; mt < 2; ++mt)
#pragma unroll
    for (int i = 0; i < 4; ++i) {
      int o = om + mt * 16 + qd * 4 + i;
      float bo = bias[o];
#pragma unroll
      for (int nt = 0; nt < 2; ++nt) {
        int bp = bp0 + nt * 16 + ln;
        int b = bp >> 10, p = bp & 1023;
        Yf[((size_t)(b * 256 + o)) * HW_ + p] = acc[mt][nt][i] + bo;
      }
    }
}

// ---------------------------------------------------------------------------
extern "C" void kernel_launch(void* const* d_in, const int* in_sizes, int n_in,
                              void* d_out, int out_size, void* d_ws, size_t ws_size,
                              hipStream_t stream)
{
  const float* query_map = (const float*)d_in[0];
  const float* kv_map    = (const float*)d_in[1];
  const float* Wq        = (const float*)d_in[2];
  const float* Wk        = (const float*)d_in[3];
  const float* Wv        = (const float*)d_in[4];
  const float* Woff1     = (const float*)d_in[5];
  const float* boff1     = (const float*)d_in[6];
  const float* Woff2     = (const float*)d_in[7];
  const float* boff2     = (const float*)d_in[8];
  const float* Wout      = (const float*)d_in[9];
  const float* bout      = (const float*)d_in[10];
  float* out = (float*)d_out;
  char* base = (char*)d_ws;

  const size_t MB = 1u << 20;
  short* qt     = (short*)(base + 1 * MB);     // 4 MB (bh,p,d) pre-scaled
  short* kt     = (short*)(base + 5 * MB);     // 4 MB tiled+swizzled
  short* vt     = (short*)(base + 9 * MB);     // 4 MB tiled+swizzled
  short* bufBh  = (short*)(base + 13 * MB);    // 4 MB q hi -> ao hi
  short* bufBl  = (short*)(base + 17 * MB);    // 4 MB q lo -> ao lo
  short* wb     = (short*)(base + 21 * MB);    // 576 KB conv weights (packed)
  short* WH     = (short*)(base + 22 * MB);    // 512 KB [Wq|Wk|Wv|Wout] packed hi
  short* WL     = (short*)(base + 23 * MB);    // 512 KB lo
  float* kvT    = (float*)(base + 24 * MB);    // 8 MB kv_map (b,p,c) f32

  prep<<<dim3(800), dim3(256), 0, stream>>>(kv_map, Wq, Wk, Wv, Wout, Woff1,
                                            WH, WL, wb, kvT);
  qgemm<<<dim3(256), dim3(512), 0, stream>>>(WH, WL, query_map,
                                             qt, bufBh, bufBl);
  convkv<<<dim3(256), dim3(512), 0, stream>>>(wb, boff1, Woff2, boff2,
                                              bufBh, bufBl, kvT, WH, WL, kt, vt);
  attn_mfma<<<dim3(256), dim3(512), 0, stream>>>(qt, kt, vt, bufBh, bufBl);
  gemm_out<<<dim3(256), dim3(512), 0, stream>>>(WH + 196608, WL + 196608,
                                                bufBh, bufBl, bout, out);
}

// Round 11
// 156.213 us; speedup vs baseline: 1.9385x; 1.0081x over previous
//
#include <hip/hip_runtime.h>

#define HW_ 1024

typedef __attribute__((ext_vector_type(8))) short bf16x8;   // 8 bf16 = 4 VGPRs
typedef __attribute__((ext_vector_type(4))) short bf16x4;   // 8 B
typedef __attribute__((ext_vector_type(4))) float f32x4;

__device__ inline unsigned short f2bf(float f) {            // RNE f32->bf16
  unsigned int u = __float_as_uint(f);
  u += 0x7FFF + ((u >> 16) & 1);
  return (unsigned short)(u >> 16);
}
__device__ inline unsigned short f2bf_fast(float f) {       // ties-away (2 ops)
  return (unsigned short)((__float_as_uint(f) + 0x8000u) >> 16);
}
__device__ inline float bf2f(unsigned short h) {
  return __uint_as_float(((unsigned int)h) << 16);
}
__device__ inline void async_copy16(const void* g, void* l) {
  __builtin_amdgcn_global_load_lds(
      (const __attribute__((address_space(1))) unsigned int*)g,
      (__attribute__((address_space(3))) unsigned int*)l, 16, 0, 0);
}

// ---------------------------------------------------------------------------
// prepQ (grid 64): pack ONLY Wq -> WH/WL slot 0 (the single prep output that
// qgemm depends on). ~1.5 us. The rest of the marshalling rides inside
// fusedQP, overlapping qgemm's compute.
// ---------------------------------------------------------------------------
__global__ __launch_bounds__(256) void prepQ(
    const float* __restrict__ Wq,
    short* __restrict__ WH, short* __restrict__ WL)
{
  const int t = threadIdx.x;
  int loc = blockIdx.x * 1024 + t * 4;  // < 65536
  float4 f4 = *(const float4*)&Wq[loc];
  float f[4] = {f4.x, f4.y, f4.z, f4.w};
  bf16x4 h4, l4;
#pragma unroll
  for (int j = 0; j < 4; ++j) {
    unsigned short h = f2bf(f[j]);
    h4[j] = (short)h;
    l4[j] = (short)f2bf(f[j] - bf2f(h));
  }
  int r = loc >> 8, c = loc & 255;      // 4 consecutive c in one 8-group
  int mtile = r >> 4, k0s = c >> 5;
  int lane_ = ((c >> 3) & 3) * 16 + (r & 15);
  int pidx = (((mtile * 8 + k0s) * 64 + lane_) * 8) + (c & 7);
  *(bf16x4*)&WH[pidx] = h4;
  *(bf16x4*)&WL[pidx] = l4;
}

// ---------------------------------------------------------------------------
// fusedQP (grid 752 x 512 thr):
//   [0,256)   qgemm (R10 verbatim; reads packed Wq from prepQ).
//   [256,512) kvT transpose (512-thr variant, correctness-proven in R8 mega).
//   [512,608) wsplit Wk/Wv/Wout -> packed slots 1..3.
//   [608,752) conv weight repack -> wb packed.
// The 496 marshalling blocks backfill CUs behind the 256 qgemm blocks, so
// prep-rest HBM traffic overlaps qgemm compute (outputs consumed next launch;
// no intra-launch reader).
// ---------------------------------------------------------------------------
__global__ __launch_bounds__(512) void fusedQP(
    const short* __restrict__ WH0, const short* __restrict__ WL0,
    const float* __restrict__ Xf,
    const float* __restrict__ kv,
    const float* __restrict__ Wk, const float* __restrict__ Wv,
    const float* __restrict__ Wo, const float* __restrict__ Woff1,
    short* __restrict__ WH, short* __restrict__ WL, short* __restrict__ wb,
    float* __restrict__ kvT,
    short* __restrict__ Yt, short* __restrict__ Yh2, short* __restrict__ Yl2)
{
  __shared__ short Bsh[32][264];
  __shared__ short Bsl[32][264];
  __shared__ float T[256][33];
  const int bid = blockIdx.x;
  const int t   = threadIdx.x;

  if (bid < 256) {                      // ---- qgemm (R10 verbatim) ----
    const int w    = t >> 6;
    const int lane = t & 63;
    const int ln   = lane & 15;
    const int qd   = lane >> 4;
    const int bp0  = bid * 32;
    const int bB   = bp0 >> 10, p0l = bp0 & 1023;

    {                                   // one-shot stage + split
      int pp = t & 31, cs = t >> 5;     // cs 0..15 -> 16 c's each
      float fv[16];
#pragma unroll
      for (int j = 0; j < 16; ++j)
        fv[j] = Xf[((size_t)(bB * 256 + cs * 16 + j)) * HW_ + p0l + pp];
#pragma unroll
      for (int g = 0; g < 4; ++g) {
        bf16x4 h4, l4;
#pragma unroll
        for (int j = 0; j < 4; ++j) {
          float f = fv[g * 4 + j];
          unsigned short h = f2bf(f);
          h4[j] = (short)h;
          l4[j] = (short)f2bf(f - bf2f(h));
        }
        *(bf16x4*)&Bsh[pp][cs * 16 + g * 4] = h4;
        *(bf16x4*)&Bsl[pp][cs * 16 + g * 4] = l4;
      }
    }
    __syncthreads();

    const int mh = w >> 2, ww = w & 3;
    const int mb = mh * 8 + ww * 2;
    f32x4 acc[2][2] = {};
#pragma unroll
    for (int k0 = 0; k0 < 256; k0 += 32) {
      const int k0s = k0 >> 5;
      bf16x8 Ah[2], Al[2], Bh[2], Bl[2];
#pragma unroll
      for (int mt = 0; mt < 2; ++mt) {  // packed: dense 1 KB wave-read
        size_t wi = ((size_t)(((mb + mt) * 8 + k0s) * 64 + lane)) * 8;
        Ah[mt] = *(const bf16x8*)&WH0[wi];
        Al[mt] = *(const bf16x8*)&WL0[wi];
      }
#pragma unroll
      for (int nt = 0; nt < 2; ++nt) {
        Bh[nt] = *(const bf16x8*)&Bsh[nt * 16 + ln][k0 + qd * 8];
        Bl[nt] = *(const bf16x8*)&Bsl[nt * 16 + ln][k0 + qd * 8];
      }
#pragma unroll
      for (int mt = 0; mt < 2; ++mt)
#pragma unroll
        for (int nt = 0; nt < 2; ++nt) {
          acc[mt][nt] = __builtin_amdgcn_mfma_f32_16x16x32_bf16(Ah[mt], Bh[nt], acc[mt][nt], 0, 0, 0);
          acc[mt][nt] = __builtin_amdgcn_mfma_f32_16x16x32_bf16(Ah[mt], Bl[nt], acc[mt][nt], 0, 0, 0);
          acc[mt][nt] = __builtin_amdgcn_mfma_f32_16x16x32_bf16(Al[mt], Bh[nt], acc[mt][nt], 0, 0, 0);
        }
    }

    const int om = mh * 128 + ww * 32;
    const float sc = 0.25506063286f;    // (1/sqrt32)*log2(e)
#pragma unroll
    for (int mt = 0; mt < 2; ++mt)
#pragma unroll
      for (int nt = 0; nt < 2; ++nt) {
        int bp = bp0 + nt * 16 + ln;
        int b = bp >> 10, p = bp & 1023;
#pragma unroll
        for (int i = 0; i < 4; ++i) {
          int o = om + mt * 16 + qd * 4 + i;
          int h = o >> 5, d = o & 31;
          Yt[(((size_t)(b * 8 + h)) * 1024 + p) * 32 + d] = (short)f2bf(acc[mt][nt][i] * sc);
        }
        int ob = om + mt * 16 + qd * 4;
        bf16x4 h4, l4;
#pragma unroll
        for (int i = 0; i < 4; ++i) {
          float f = acc[mt][nt][i];
          unsigned short h = f2bf(f);
          h4[i] = (short)h;
          l4[i] = (short)f2bf(f - bf2f(h));
        }
        *(bf16x4*)&Yh2[(size_t)bp * 256 + ob] = h4;
        *(bf16x4*)&Yl2[(size_t)bp * 256 + ob] = l4;
      }

  } else if (bid < 512) {               // ---- kvT transpose (512-thr) ----
    int tb = bid - 256;
    int b = tb >> 5, p0 = (tb & 31) * 32;
    int pp = t & 31, cg16 = t >> 5;     // cg16 0..15
#pragma unroll
    for (int i = 0; i < 16; ++i) {
      int c = cg16 * 16 + i;
      T[c][pp] = kv[((size_t)(b * 256 + c)) * HW_ + p0 + pp];
    }
    __syncthreads();
#pragma unroll
    for (int r = 0; r < 4; ++r) {
      int e = t + 512 * r;
      int c4 = (e & 63) * 4, pp2 = e >> 6;
      float4 v4;
      v4.x = T[c4 + 0][pp2];
      v4.y = T[c4 + 1][pp2];
      v4.z = T[c4 + 2][pp2];
      v4.w = T[c4 + 3][pp2];
      *(float4*)&kvT[((size_t)(b * 1024 + p0 + pp2)) * 256 + c4] = v4;
    }
  } else if (bid < 608) {               // ---- wsplit Wk/Wv/Wout ----
    int g = (bid - 512) * 2048 + t * 4; // < 196608
    int mat = 1 + (g >> 16);            // 1..3
    int loc = g & 65535;
    const float* W = (mat == 1) ? Wk : (mat == 2) ? Wv : Wo;
    float4 f4 = *(const float4*)&W[loc];
    float f[4] = {f4.x, f4.y, f4.z, f4.w};
    bf16x4 h4, l4;
#pragma unroll
    for (int j = 0; j < 4; ++j) {
      unsigned short h = f2bf(f[j]);
      h4[j] = (short)h;
      l4[j] = (short)f2bf(f[j] - bf2f(h));
    }
    int r = loc >> 8, c = loc & 255;
    int mtile = r >> 4, k0s = c >> 5;
    int lane_ = ((c >> 3) & 3) * 16 + (r & 15);
    int pidx = (((mtile * 8 + k0s) * 64 + lane_) * 8) + (c & 7);
    *(bf16x4*)&WH[mat * 65536 + pidx] = h4;
    *(bf16x4*)&WL[mat * 65536 + pidx] = l4;
  } else {                              // ---- conv weight repack ----
    int e0 = (bid - 608) * 2048 + t * 4;  // < 294912
    int c = e0 & 255;
    int o = (e0 >> 8) & 127;
    int tap = e0 >> 15;
    bf16x4 h4;
#pragma unroll
    for (int j = 0; j < 4; ++j)
      h4[j] = (short)f2bf(Woff1[((size_t)(o * 256 + c + j)) * 9 + tap]);
    int otile = o >> 4, c0s = c >> 5;
    int lane_ = ((c >> 3) & 3) * 16 + (o & 15);
    int widx = ((((tap * 8 + otile) * 8 + c0s) * 64 + lane_) * 8) + (c & 7);
    *(bf16x4*)&wb[widx] = h4;
  }
}

// ---------------------------------------------------------------------------
// convkv (R10 verbatim): one-shot staging + c0-split conv + offset head +
// sampling + K/V GEMM, packed weights. grid 256, 512 thr, LDS 139.5 KB.
// ---------------------------------------------------------------------------
__global__ __launch_bounds__(512) void convkv(
    const short* __restrict__ wb, const float* __restrict__ bias,
    const float* __restrict__ W2, const float* __restrict__ b2,
    const short* __restrict__ xh, const short* __restrict__ xl,
    const float* __restrict__ kvT,
    const short* __restrict__ WH, const short* __restrict__ WL,
    short* __restrict__ kt, short* __restrict__ vt)
{
  __shared__ short Xs[2][3][34][264];
  __shared__ short XsH[32][264];
  __shared__ short XsL[32][264];
  __shared__ float red[4][32][2];
  __shared__ float2 crd[32];
  const int id   = blockIdx.x;          // 256
  const int b    = id & 7;
  const int y0   = id >> 3;
  const int t    = threadIdx.x;
  const int w    = t >> 6;
  const int lane = t & 63;
  const int ln   = lane & 15;
  const int qd   = lane >> 4;
  const int bp0  = (b * 32 + y0) * 32;

  // phase 0: one-shot staging
  {
    bf16x8 v[12];
#pragma unroll
    for (int i = 0; i < 12; ++i) {
      int e = t + 512 * i;
      int oct = e & 31;
      int x   = (e >> 5) & 31;
      int rr  = e >> 10;
      int hl  = rr / 3, r = rr % 3;
      int yy  = y0 + r - 1;
      bf16x8 val = {};
      if (yy >= 0 && yy < 32) {
        const short* src = hl ? xl : xh;
        val = *(const bf16x8*)&src[((size_t)((b * 32 + yy) * 32 + x)) * 256 + oct * 8];
      }
      v[i] = val;
    }
#pragma unroll
    for (int i = 0; i < 12; ++i) {
      int e = t + 512 * i;
      int oct = e & 31;
      int x   = (e >> 5) & 31;
      int rr  = e >> 10;
      int hl  = rr / 3, r = rr % 3;
      *(bf16x8*)&Xs[hl][r][x + 1][oct * 8] = v[i];
    }
    if (t < 384) {
      int oct  = t & 31;
      int colw = (t >> 5) & 1;
      int rr   = t >> 6;
      int hl   = rr / 3, r = rr % 3;
      bf16x8 zz = {};
      *(bf16x8*)&Xs[hl][r][colw ? 33 : 0][oct * 8] = zz;
    }
  }
  __syncthreads();

  // phase 1: conv3x3, c0-split across wave-halves
  const int chh = w >> 2;
  const int ow  = w & 3;
  const int o0c = ow * 32;
  f32x4 acc[2][2] = {};
#pragma unroll
  for (int c0s = 0; c0s < 4; ++c0s) {
    const int c0 = chh * 128 + c0s * 32;
    const int c0abs = chh * 4 + c0s;
#pragma unroll
    for (int tap = 0; tap < 9; ++tap) {
      const int ky = tap / 3, kx = tap % 3;
      bf16x8 afr[2];
#pragma unroll
      for (int m = 0; m < 2; ++m)
        afr[m] = *(const bf16x8*)&wb[((((tap * 8 + (ow * 2 + m)) * 8 + c0abs) * 64
                                       + lane) * 8)];
#pragma unroll
      for (int nt = 0; nt < 2; ++nt) {
        int hc = nt * 16 + ln + kx;
        bf16x8 bh = *(const bf16x8*)&Xs[0][ky][hc][c0 + qd * 8];
        bf16x8 bl = *(const bf16x8*)&Xs[1][ky][hc][c0 + qd * 8];
#pragma unroll
        for (int m = 0; m < 2; ++m) {
          acc[m][nt] = __builtin_amdgcn_mfma_f32_16x16x32_bf16(afr[m], bh, acc[m][nt], 0, 0, 0);
          acc[m][nt] = __builtin_amdgcn_mfma_f32_16x16x32_bf16(afr[m], bl, acc[m][nt], 0, 0, 0);
        }
      }
    }
  }

  float* ps = (float*)&XsH[0][0];
  if (w >= 4) {
#pragma unroll
    for (int m = 0; m < 2; ++m)
#pragma unroll
      for (int nt = 0; nt < 2; ++nt)
        *(f32x4*)&ps[(((w - 4) * 64 + lane) * 4 + m * 2 + nt) * 4] = acc[m][nt];
  }
  __syncthreads();

  // phase 2: offset head -> coords
  if (w < 4) {
    float ps0[2] = {0.f, 0.f}, ps1[2] = {0.f, 0.f};
#pragma unroll
    for (int m = 0; m < 2; ++m)
#pragma unroll
      for (int nt = 0; nt < 2; ++nt) {
        f32x4 p = *(const f32x4*)&ps[((w * 64 + lane) * 4 + m * 2 + nt) * 4];
        acc[m][nt] += p;
      }
#pragma unroll
    for (int m = 0; m < 2; ++m)
#pragma unroll
      for (int i = 0; i < 4; ++i) {
        int o = o0c + m * 16 + qd * 4 + i;
        float bo = bias[o];
        float w2a = W2[o], w2b = W2[128 + o];
#pragma unroll
        for (int nt = 0; nt < 2; ++nt) {
          float h = fmaxf(acc[m][nt][i] + bo, 0.f);
          ps0[nt] += w2a * h;
          ps1[nt] += w2b * h;
        }
      }
#pragma unroll
    for (int msk = 16; msk < 64; msk <<= 1) {
      ps0[0] += __shfl_xor(ps0[0], msk, 64);
      ps0[1] += __shfl_xor(ps0[1], msk, 64);
      ps1[0] += __shfl_xor(ps1[0], msk, 64);
      ps1[1] += __shfl_xor(ps1[1], msk, 64);
    }
    if (qd == 0) {
#pragma unroll
      for (int nt = 0; nt < 2; ++nt) {
        red[w][nt * 16 + ln][0] = ps0[nt];
        red[w][nt * 16 + ln][1] = ps1[nt];
      }
    }
  }
  __syncthreads();
  if (t < 32) {
    float c0s = (red[0][t][0] + red[1][t][0]) + (red[2][t][0] + red[3][t][0]) + b2[0];
    float c1s = (red[0][t][1] + red[1][t][1]) + (red[2][t][1] + red[3][t][1]) + b2[1];
    float gx = -1.f + 2.f * (float)t / 31.f;
    float gy = -1.f + 2.f * (float)y0 / 31.f;
    float vx = gx + 0.1f * c0s;
    float vy = gy + 0.1f * c1s;
    float px = fminf(fmaxf((vx + 1.f) * 0.5f * 31.f, 0.f), 31.f);
    float py = fminf(fmaxf((vy + 1.f) * 0.5f * 31.f, 0.f), 31.f);
    crd[t] = make_float2(px, py);
  }
  __syncthreads();

  // phase 3: sampling + K/V GEMM
#pragma unroll
  for (int it = 0; it < 2; ++it) {
    int e = t + 512 * it;
    int oct = e & 31, row = e >> 5;
    float2 cd = crd[row];
    float x0f = floorf(cd.x), y0f = floorf(cd.y);
    float wx = cd.x - x0f, wy = cd.y - y0f;
    int x0 = (int)x0f, y0i = (int)y0f;
    int x1 = min(x0 + 1, 31), y1 = min(y0i + 1, 31);
    float w00 = (1.f - wx) * (1.f - wy), w01 = wx * (1.f - wy);
    float w10 = (1.f - wx) * wy,         w11 = wx * wy;
    const float* r00 = &kvT[((size_t)(b * 1024 + y0i * 32 + x0)) * 256 + oct * 8];
    const float* r01 = &kvT[((size_t)(b * 1024 + y0i * 32 + x1)) * 256 + oct * 8];
    const float* r10 = &kvT[((size_t)(b * 1024 + y1 * 32 + x0)) * 256 + oct * 8];
    const float* r11 = &kvT[((size_t)(b * 1024 + y1 * 32 + x1)) * 256 + oct * 8];
    float4 a00 = *(const float4*)r00, b00 = *(const float4*)(r00 + 4);
    float4 a01 = *(const float4*)r01, b01 = *(const float4*)(r01 + 4);
    float4 a10 = *(const float4*)r10, b10 = *(const float4*)(r10 + 4);
    float4 a11 = *(const float4*)r11, b11 = *(const float4*)(r11 + 4);
    float v[8];
    v[0] = a00.x * w00 + a01.x * w01 + a10.x * w10 + a11.x * w11;
    v[1] = a00.y * w00 + a01.y * w01 + a10.y * w10 + a11.y * w11;
    v[2] = a00.z * w00 + a01.z * w01 + a10.z * w10 + a11.z * w11;
    v[3] = a00.w * w00 + a01.w * w01 + a10.w * w10 + a11.w * w11;
    v[4] = b00.x * w00 + b01.x * w01 + b10.x * w10 + b11.x * w11;
    v[5] = b00.y * w00 + b01.y * w01 + b10.y * w10 + b11.y * w11;
    v[6] = b00.z * w00 + b01.z * w01 + b10.z * w10 + b11.z * w11;
    v[7] = b00.w * w00 + b01.w * w01 + b10.w * w10 + b11.w * w11;
    bf16x8 h8, l8;
#pragma unroll
    for (int j = 0; j < 8; ++j) {
      unsigned short h = f2bf(v[j]);
      h8[j] = (short)h;
      l8[j] = (short)f2bf(v[j] - bf2f(h));
    }
    *(bf16x8*)&XsH[row][oct * 8] = h8;
    *(bf16x8*)&XsL[row][oct * 8] = l8;
  }
  __syncthreads();

  const int mat  = w >> 2;
  const short* WAh = WH + (mat ? 131072 : 65536);
  const short* WAl = WL + (mat ? 131072 : 65536);
  const int om4 = (w & 3) * 4;

  f32x4 acg[4][2] = {};
#pragma unroll
  for (int k0 = 0; k0 < 256; k0 += 32) {
    const int k0s = k0 >> 5;
    bf16x8 Bh[2], Bl[2];
#pragma unroll
    for (int nt = 0; nt < 2; ++nt) {
      Bh[nt] = *(const bf16x8*)&XsH[nt * 16 + ln][k0 + qd * 8];
      Bl[nt] = *(const bf16x8*)&XsL[nt * 16 + ln][k0 + qd * 8];
    }
#pragma unroll
    for (int mt = 0; mt < 4; ++mt) {
      size_t wi = ((size_t)(((om4 + mt) * 8 + k0s) * 64 + lane)) * 8;
      bf16x8 Ah = *(const bf16x8*)&WAh[wi];
      bf16x8 Al = *(const bf16x8*)&WAl[wi];
#pragma unroll
      for (int nt = 0; nt < 2; ++nt) {
        acg[mt][nt] = __builtin_amdgcn_mfma_f32_16x16x32_bf16(Ah, Bh[nt], acg[mt][nt], 0, 0, 0);
        acg[mt][nt] = __builtin_amdgcn_mfma_f32_16x16x32_bf16(Ah, Bl[nt], acg[mt][nt], 0, 0, 0);
        acg[mt][nt] = __builtin_amdgcn_mfma_f32_16x16x32_bf16(Al, Bh[nt], acg[mt][nt], 0, 0, 0);
      }
    }
  }

#pragma unroll
  for (int mt = 0; mt < 4; ++mt)
#pragma unroll
    for (int nt = 0; nt < 2; ++nt) {
      int p  = bp0 + nt * 16 + ln;
      int pl = p & 1023;
      int jt = pl >> 6, jl = pl & 63;
#pragma unroll
      for (int i = 0; i < 4; ++i) {
        int oc = (w & 3) * 64 + mt * 16 + qd * 4 + i;
        unsigned short val = f2bf(acg[mt][nt][i]);
        int bhead = b * 8 + (oc >> 5), d = oc & 31;
        if (mat == 0) {
          int cd2 = (d >> 3) ^ ((jl >> 2) & 3);
          kt[((((size_t)(bhead * 16 + jt)) * 64 + jl) * 4 + cd2) * 8 + (d & 7)] = (short)val;
        } else {
          int jjs = ((jl & 15) << 2) | (jl >> 4);       // sigma
          int cj = (jjs >> 3) ^ (d & 7);
          vt[((((size_t)(bhead * 16 + jt)) * 32 + d) * 8 + cj) * 8 + (jjs & 7)] = (short)val;
        }
      }
    }
}

// ---------------------------------------------------------------------------
// MFMA flash attention, PAIRED (R10 verbatim): grid 256 x 512 thr, shared
// K/V double-buffer per (bh, qp) pair.
// ---------------------------------------------------------------------------
__global__ __launch_bounds__(512) void attn_mfma(
    const short* __restrict__ qt, const short* __restrict__ kt,
    const short* __restrict__ vt, short* __restrict__ aoh,
    short* __restrict__ aol)
{
  __shared__ __align__(16) short Ks[2][2048];
  __shared__ __align__(16) short Vs[2][2048];
  __shared__ __align__(16) short P[8][32][72];
  const int t    = threadIdx.x;
  const int w    = t >> 6;              // 0..7
  const int lane = t & 63;
  const int ln   = lane & 15;
  const int qd   = lane >> 4;
  const int bid  = blockIdx.x;          // 256
  const int b    = bid & 7;
  const int rem2 = bid >> 3;            // 0..31
  const int h    = rem2 & 7;
  const int qp   = rem2 >> 3;           // 0..3
  const int bh   = b * 8 + h;
  const int qce  = qp + 4 * (w >> 2);   // qc: waves 0-3 -> qp, 4-7 -> qp+4
  const int qbase = qce * 128 + (w & 3) * 16;

  const short* ktb = kt + (size_t)bh * 32768;
  const short* vtb = vt + (size_t)bh * 32768;

  bf16x8 aq[2];
  aq[0] = *(const bf16x8*)&qt[((size_t)(bh * 1024 + qbase + ln)) * 32 + qd * 8];
  aq[1] = *(const bf16x8*)&qt[((size_t)(bh * 1024 + qbase + 64 + ln)) * 32 + qd * 8];

  f32x4 acc[2][2] = {};
  float lacc[2][4] = {};
  const f32x4 zero = {0.f, 0.f, 0.f, 0.f};

  const int sgw   = w & 3;
  const int stoff = sgw * 512 + lane * 8;
  const int ldoff = sgw * 512;

  if (w < 4) async_copy16(&ktb[stoff], &Ks[0][ldoff]);
  else       async_copy16(&vtb[stoff], &Vs[0][ldoff]);
  __syncthreads();

  for (int jt = 0; jt < 16; ++jt) {
    const int cur = jt & 1, nxt = cur ^ 1;
    if (jt < 15) {
      if (w < 4) async_copy16(&ktb[(jt + 1) * 2048 + stoff], &Ks[nxt][ldoff]);
      else       async_copy16(&vtb[(jt + 1) * 2048 + stoff], &Vs[nxt][ldoff]);
    }

    bf16x8 bk[4], bv[2][2];
#pragma unroll
    for (int kk = 0; kk < 4; ++kk)
      bk[kk] = *(const bf16x8*)&Ks[cur][((kk * 16 + ln) * 4 + (qd ^ ((ln >> 2) & 3))) * 8];
#pragma unroll
    for (int kc = 0; kc < 2; ++kc)
#pragma unroll
      for (int ds = 0; ds < 2; ++ds)
        bv[kc][ds] = *(const bf16x8*)&Vs[cur][((ds * 16 + ln) * 8 + ((kc * 4 + qd) ^ (ln & 7))) * 8];

#pragma unroll
    for (int qf = 0; qf < 2; ++qf) {
      f32x4 s[4];
      __builtin_amdgcn_s_setprio(1);
#pragma unroll
      for (int kk = 0; kk < 4; ++kk)
        s[kk] = __builtin_amdgcn_mfma_f32_16x16x32_bf16(aq[qf], bk[kk], zero, 0, 0, 0);
      __builtin_amdgcn_s_setprio(0);

#pragma unroll
      for (int i = 0; i < 4; ++i) {
        float p0 = __builtin_amdgcn_exp2f(s[0][i]);
        float p1 = __builtin_amdgcn_exp2f(s[1][i]);
        float p2 = __builtin_amdgcn_exp2f(s[2][i]);
        float p3 = __builtin_amdgcn_exp2f(s[3][i]);
        s[0][i] = p0; s[1][i] = p1; s[2][i] = p2; s[3][i] = p3;
        lacc[qf][i] += (p0 + p1) + (p2 + p3);
      }
#pragma unroll
      for (int i = 0; i < 4; ++i) {
        bf16x4 p4;
#pragma unroll
        for (int kk = 0; kk < 4; ++kk) p4[kk] = (short)f2bf_fast(s[kk][i]);
        *(bf16x4*)&P[w][qf * 16 + qd * 4 + i][4 * ln] = p4;
      }
      __builtin_amdgcn_s_setprio(1);
#pragma unroll
      for (int kc = 0; kc < 2; ++kc) {
        bf16x8 ap = *(const bf16x8*)&P[w][qf * 16 + ln][kc * 32 + qd * 8];
#pragma unroll
        for (int ds = 0; ds < 2; ++ds)
          acc[qf][ds] = __builtin_amdgcn_mfma_f32_16x16x32_bf16(ap, bv[kc][ds], acc[qf][ds], 0, 0, 0);
      }
      __builtin_amdgcn_s_setprio(0);
    }

    __syncthreads();
  }

  const int bb = bh >> 3, hh2 = bh & 7;
#pragma unroll
  for (int qf = 0; qf < 2; ++qf)
#pragma unroll
    for (int i = 0; i < 4; ++i) {
      float l = lacc[qf][i];
      l += __shfl_xor(l, 1, 64);
      l += __shfl_xor(l, 2, 64);
      l += __shfl_xor(l, 4, 64);
      l += __shfl_xor(l, 8, 64);
      float inv = 1.f / l;
      int qrow = qbase + qf * 64 + qd * 4 + i;
#pragma unroll
      for (int ds = 0; ds < 2; ++ds) {
        float v = acc[qf][ds][i] * inv;
        unsigned short hv = f2bf(v);
        size_t idx = ((size_t)(bb * 1024 + qrow)) * 256 + hh2 * 32 + ds * 16 + ln;
        aoh[idx] = (short)hv;
        aol[idx] = (short)f2bf(v - bf2f(hv));
      }
    }
}

// ---------------------------------------------------------------------------
// Output GEMM (R10 verbatim): 512 thr, grid 256, shared X tile, packed Wout.
// ---------------------------------------------------------------------------
__global__ __launch_bounds__(512) void gemm_out(
    const short* __restrict__ Wh, const short* __restrict__ Wl,
    const short* __restrict__ Xh, const short* __restrict__ Xl,
    const float* __restrict__ bias, float* __restrict__ Yf)
{
  __shared__ short XsH[32][264];
  __shared__ short XsL[32][264];
  const int t    = threadIdx.x;
  const int w    = t >> 6;              // 0..7
  const int lane = t & 63;
  const int ln   = lane & 15;
  const int qd   = lane >> 4;
  const int bp0  = blockIdx.x * 32;

#pragma unroll
  for (int it = 0; it < 2; ++it) {      // stage X tile: dense 16B loads
    int e = t + 512 * it;
    int oct = e & 31, row = e >> 5;
    bf16x8 vh = *(const bf16x8*)&Xh[((size_t)(bp0 + row)) * 256 + oct * 8];
    bf16x8 vl = *(const bf16x8*)&Xl[((size_t)(bp0 + row)) * 256 + oct * 8];
    *(bf16x8*)&XsH[row][oct * 8] = vh;
    *(bf16x8*)&XsL[row][oct * 8] = vl;
  }
  __syncthreads();

  const int mh = w >> 2, ww = w & 3;
  const int mb = mh * 8 + ww * 2;
  f32x4 acc[2][2] = {};
#pragma unroll
  for (int k0 = 0; k0 < 256; k0 += 32) {
    const int k0s = k0 >> 5;
    bf16x8 Ah[2], Al[2], Bh[2], Bl[2];
#pragma unroll
    for (int mt = 0; mt < 2; ++mt) {    // packed: dense 1 KB wave-read
      size_t wi = ((size_t)(((mb + mt) * 8 + k0s) * 64 + lane)) * 8;
      Ah[mt] = *(const bf16x8*)&Wh[wi];
      Al[mt] = *(const bf16x8*)&Wl[wi];
    }
#pragma unroll
    for (int nt = 0; nt < 2; ++nt) {
      Bh[nt] = *(const bf16x8*)&XsH[nt * 16 + ln][k0 + qd * 8];
      Bl[nt] = *(const bf16x8*)&XsL[nt * 16 + ln][k0 + qd * 8];
    }
#pragma unroll
    for (int mt = 0; mt < 2; ++mt)
#pragma unroll
      for (int nt = 0; nt < 2; ++nt) {
        acc[mt][nt] = __builtin_amdgcn_mfma_f32_16x16x32_bf16(Ah[mt], Bh[nt], acc[mt][nt], 0, 0, 0);
        acc[mt][nt] = __builtin_amdgcn_mfma_f32_16x16x32_bf16(Ah[mt], Bl[nt], acc[mt][nt], 0, 0, 0);
        acc[mt][nt] = __builtin_amdgcn_mfma_f32_16x16x32_bf16(Al[mt], Bh[nt], acc[mt][nt], 0, 0, 0);
      }
  }

  const int om = mh * 128 + ww * 32;
#pragma unroll
  for (int mt = 0; mt < 2; ++mt)
#pragma unroll
    for (int i = 0; i < 4; ++i) {
      int o = om + mt * 16 + qd * 4 + i;
      float bo = bias[o];
#pragma unroll
      for (int nt = 0; nt < 2; ++nt) {
        int bp = bp0 + nt * 16 + ln;
        int b = bp >> 10, p = bp & 1023;
        Yf[((size_t)(b * 256 + o)) * HW_ + p] = acc[mt][nt][i] + bo;
      }
    }
}

// ---------------------------------------------------------------------------
extern "C" void kernel_launch(void* const* d_in, const int* in_sizes, int n_in,
                              void* d_out, int out_size, void* d_ws, size_t ws_size,
                              hipStream_t stream)
{
  const float* query_map = (const float*)d_in[0];
  const float* kv_map    = (const float*)d_in[1];
  const float* Wq        = (const float*)d_in[2];
  const float* Wk        = (const float*)d_in[3];
  const float* Wv        = (const float*)d_in[4];
  const float* Woff1     = (const float*)d_in[5];
  const float* boff1     = (const float*)d_in[6];
  const float* Woff2     = (const float*)d_in[7];
  const float* boff2     = (const float*)d_in[8];
  const float* Wout      = (const float*)d_in[9];
  const float* bout      = (const float*)d_in[10];
  float* out = (float*)d_out;
  char* base = (char*)d_ws;

  const size_t MB = 1u << 20;
  short* qt     = (short*)(base + 1 * MB);     // 4 MB (bh,p,d) pre-scaled
  short* kt     = (short*)(base + 5 * MB);     // 4 MB tiled+swizzled
  short* vt     = (short*)(base + 9 * MB);     // 4 MB tiled+swizzled
  short* bufBh  = (short*)(base + 13 * MB);    // 4 MB q hi -> ao hi
  short* bufBl  = (short*)(base + 17 * MB);    // 4 MB q lo -> ao lo
  short* wb     = (short*)(base + 21 * MB);    // 576 KB conv weights (packed)
  short* WH     = (short*)(base + 22 * MB);    // 512 KB [Wq|Wk|Wv|Wout] packed hi
  short* WL     = (short*)(base + 23 * MB);    // 512 KB lo
  float* kvT    = (float*)(base + 24 * MB);    // 8 MB kv_map (b,p,c) f32

  prepQ<<<dim3(64), dim3(256), 0, stream>>>(Wq, WH, WL);
  fusedQP<<<dim3(752), dim3(512), 0, stream>>>(WH, WL, query_map,
                                               kv_map, Wk, Wv, Wout, Woff1,
                                               WH, WL, wb, kvT,
                                               qt, bufBh, bufBl);
  convkv<<<dim3(256), dim3(512), 0, stream>>>(wb, boff1, Woff2, boff2,
                                              bufBh, bufBl, kvT, WH, WL, kt, vt);
  attn_mfma<<<dim3(256), dim3(512), 0, stream>>>(qt, kt, vt, bufBh, bufBl);
  gemm_out<<<dim3(256), dim3(512), 0, stream>>>(WH + 196608, WL + 196608,
                                                bufBh, bufBl, bout, out);
}